// Round 1
// baseline (417.627 us; speedup 1.0000x reference)
//
#include <hip/hip_runtime.h>

typedef unsigned short u16;
typedef __bf16  bfrag  __attribute__((ext_vector_type(8)));   // MFMA A/B operand (4 VGPRs)
typedef float   f32x4  __attribute__((ext_vector_type(4)));   // MFMA C/D operand
typedef u16     u16x8  __attribute__((ext_vector_type(8)));
typedef u16     u16x4  __attribute__((ext_vector_type(4)));

__device__ __forceinline__ float bf2f(u16 u) {
    unsigned v = ((unsigned)u) << 16;
    return __builtin_bit_cast(float, v);
}
__device__ __forceinline__ u16 f2bf(float f) {   // round-to-nearest-even
    unsigned x = __builtin_bit_cast(unsigned, f);
    unsigned r = (x + 0x7fffu + ((x >> 16) & 1u)) >> 16;
    return (u16)r;
}
__device__ __forceinline__ void g2l16(const u16* g, u16* l) {
    // 16B per lane -> lds_base + lane*16 (wave-uniform LDS base)
    __builtin_amdgcn_global_load_lds((__attribute__((address_space(1))) void*)g,
                                     (__attribute__((address_space(3))) void*)l, 16, 0, 0);
}
__device__ __forceinline__ float gelu_tanh(float x) {
    // 0.5x(1+tanh(c)) == x * sigmoid(2c)
    float c = 1.5957691216057308f * (x + 0.044715f * x * x * x);
    return x * __frcp_rn(1.0f + __expf(-c));
}

// BK=64 LDS tiles: row = 128 B = 8 chunks of 16 B = exactly one 32-bank stripe.
// Swizzle phys_chunk = logical_chunk ^ (row & 7): conflict-free frag reads.
#define SW64(l)   (((((l) & 7) ^ (((l) >> 3) & 7))) * 8)
#define RS64(kk, quad, l15)  (((((kk) * 4 + (quad)) ^ ((l15) & 7))) * 8)

// ---------------- weight transposes + LN1 fused in ONE kernel ---------------
// W1/W2 now emitted in INTERLEAVED layout W12I: 64-col groups alternate
// (W1 group q -> rows 128q..128q+63, W2 group q -> rows 128q+64..128q+127),
// so the 8-phase GeGLU GEMM reads a contiguous 256-row B panel per block.
__global__ __launch_bounds__(256) void wtln(
        const float* __restrict__ Wq, const float* __restrict__ Wk,
        const float* __restrict__ Wv, const float* __restrict__ Wo,
        const float* __restrict__ W1, const float* __restrict__ W2,
        const float* __restrict__ W3,
        u16* __restrict__ WqkvT, u16* __restrict__ WoT,
        u16* __restrict__ W12T, u16* __restrict__ W3T,
        const float* __restrict__ x, const float* __restrict__ ln1_s,
        const float* __restrict__ ln1_b, u16* __restrict__ xn1) {
    __shared__ float tile[32][33];
    int blk = blockIdx.x;
    if (blk >= 16384) {
        int row = blk - 16384, t = threadIdx.x;
        float4 v = ((const float4*)(x + (size_t)row * 1024))[t];
        float sum = v.x + v.y + v.z + v.w;
        float sq  = v.x * v.x + v.y * v.y + v.z * v.z + v.w * v.w;
#pragma unroll
        for (int off = 1; off < 64; off <<= 1) {
            sum += __shfl_xor(sum, off);
            sq  += __shfl_xor(sq,  off);
        }
        float* s1 = &tile[0][0];
        float* s2 = &tile[0][8];
        int wave = t >> 6;
        if ((t & 63) == 0) { s1[wave] = sum; s2[wave] = sq; }
        __syncthreads();
        sum = s1[0] + s1[1] + s1[2] + s1[3];
        sq  = s2[0] + s2[1] + s2[2] + s2[3];
        float mean = sum * (1.0f / 1024.0f);
        float var  = sq  * (1.0f / 1024.0f) - mean * mean;
        float inv  = rsqrtf(var + 1e-6f);
        float4 sc = ((const float4*)ln1_s)[t], bb = ((const float4*)ln1_b)[t];
        u16x4 o;
        o[0] = f2bf((v.x - mean) * inv * sc.x + bb.x);
        o[1] = f2bf((v.y - mean) * inv * sc.y + bb.y);
        o[2] = f2bf((v.z - mean) * inv * sc.z + bb.z);
        o[3] = f2bf((v.w - mean) * inv * sc.w + bb.w);
        *(u16x4*)&xn1[(size_t)row * 1024 + t * 4] = o;
        return;
    }
    const float* W; u16* Wt; int R, C, local; int ilv = -1;
    if (blk < 3072) {
        int w = blk >> 10; local = blk & 1023;
        W = (w == 0) ? Wq : (w == 1) ? Wk : Wv;
        Wt = WqkvT + (size_t)w * 1024 * 1024; R = 1024; C = 1024;
    } else if (blk < 4096) { W = Wo; Wt = WoT; R = 1024; C = 1024; local = blk - 3072; }
    else if (blk < 8192)   { W = W1; Wt = W12T; R = 1024; C = 4096; local = blk - 4096; ilv = 0; }
    else if (blk < 12288)  { W = W2; Wt = W12T; R = 1024; C = 4096; local = blk - 8192; ilv = 1; }
    else                   { W = W3; Wt = W3T; R = 4096; C = 1024; local = blk - 12288; }
    int tiles_x = C >> 5;
    int c0 = (local % tiles_x) * 32, r0 = (local / tiles_x) * 32;
    int tx = threadIdx.x & 31, ty = threadIdx.x >> 5;
#pragma unroll
    for (int i = 0; i < 32; i += 8)
        tile[ty + i][tx] = W[(size_t)(r0 + ty + i) * C + c0 + tx];
    __syncthreads();
#pragma unroll
    for (int i = 0; i < 32; i += 8) {
        int c = c0 + ty + i;
        int orow = (ilv < 0) ? c : ((c >> 6) * 128 + ilv * 64 + (c & 63));
        Wt[(size_t)orow * R + r0 + tx] = f2bf(tile[tx][ty + i]);
    }
}

// ---- gemm64: 4-wave 128x128 block tile, 64x64 wave tile, BK=64 -------------
// EPI 0: bf16 partial store to o[kz] (split-K) | 4: QKV + per-head LN.
template <int EPI>
__global__ __launch_bounds__(256, 3) void gemm64(const u16* __restrict__ A,
                                                 const u16* __restrict__ Bt,
                                                 const float* __restrict__ bias,
                                                 const float* __restrict__ bias2,
                                                 const float* __restrict__ bias3,
                                                 const float* __restrict__ qn_s,
                                                 const float* __restrict__ qn_b,
                                                 const float* __restrict__ kn_s,
                                                 const float* __restrict__ kn_b,
                                                 u16* __restrict__ o0,
                                                 u16* __restrict__ o1,
                                                 u16* __restrict__ o2,
                                                 u16* __restrict__ o3,
                                                 int M, int N, int K, int Klen) {
    __shared__ u16 As[128 * 64];
    __shared__ u16 Bs[128 * 64];
    int tid = threadIdx.x, wave = tid >> 6, lane = tid & 63;
    int quad = lane >> 4, l15 = lane & 15;
    int row0 = blockIdx.y * 128, col0 = blockIdx.x * 128;
    int kz = blockIdx.z;
    int wr = (wave >> 1) * 64, wc = (wave & 1) * 64;
    int swz = SW64(lane);

    f32x4 acc[4][4] = {};

    const u16* gA = A  + (size_t)(row0 + wave * 32 + (lane >> 3)) * K + kz * Klen + swz;
    const u16* gB = Bt + (size_t)(col0 + wave * 32 + (lane >> 3)) * K + kz * Klen + swz;
    u16* lA = &As[wave * 32 * 64];
    u16* lB = &Bs[wave * 32 * 64];

    for (int k0 = 0; k0 < Klen; k0 += 64) {
        __syncthreads();
#pragma unroll
        for (int j = 0; j < 4; j++) {
            g2l16(gA + k0 + j * 8 * K, lA + j * 8 * 64);
            g2l16(gB + k0 + j * 8 * K, lB + j * 8 * 64);
        }
        __syncthreads();
#pragma unroll
        for (int kk = 0; kk < 2; kk++) {
            int rs = RS64(kk, quad, l15);
            bfrag af[4], bf[4];
#pragma unroll
            for (int mi = 0; mi < 4; mi++)
                af[mi] = *(const bfrag*)&As[(wr + mi * 16 + l15) * 64 + rs];
#pragma unroll
            for (int ni = 0; ni < 4; ni++)
                bf[ni] = *(const bfrag*)&Bs[(wc + ni * 16 + l15) * 64 + rs];
#pragma unroll
            for (int mi = 0; mi < 4; mi++)
#pragma unroll
                for (int ni = 0; ni < 4; ni++)
                    acc[mi][ni] = __builtin_amdgcn_mfma_f32_16x16x32_bf16(
                        af[mi], bf[ni], acc[mi][ni], 0, 0, 0);
        }
    }

    if (EPI == 0) {
        u16* P = (kz == 0) ? o0 : (kz == 1) ? o1 : (kz == 2) ? o2 : o3;
#pragma unroll
        for (int mi = 0; mi < 4; mi++) {
            int rbase = row0 + wr + mi * 16 + quad * 4;
#pragma unroll
            for (int r = 0; r < 4; r++)
#pragma unroll
                for (int ni = 0; ni < 4; ni++)
                    P[(size_t)(rbase + r) * N + col0 + wc + ni * 16 + l15] =
                        f2bf(acc[mi][ni][r]);
        }
    } else {
        int cbase = col0 + wc;
        int z = cbase >> 10;              // 0=q, 1=k, 2=v
        int hd = (cbase >> 6) & 15;
        const float* bp = (z == 0) ? bias : (z == 1) ? bias2 : bias3;
        float post = (z == 0) ? 0.125f : 1.0f;
        float bv[4], sn[4], bn[4];
#pragma unroll
        for (int ni = 0; ni < 4; ni++)
            bv[ni] = bp[(cbase & 1023) + ni * 16 + l15];
        if (z < 2) {
            const float* ns = (z == 0) ? qn_s : kn_s;
            const float* nb = (z == 0) ? qn_b : kn_b;
#pragma unroll
            for (int ni = 0; ni < 4; ni++) {
                sn[ni] = ns[hd * 64 + ni * 16 + l15];
                bn[ni] = nb[hd * 64 + ni * 16 + l15];
            }
        }
#pragma unroll
        for (int mi = 0; mi < 4; mi++) {
            int rbase = row0 + wr + mi * 16 + quad * 4;
#pragma unroll
            for (int r = 0; r < 4; r++) {
                float v0 = acc[mi][0][r] + bv[0];
                float v1 = acc[mi][1][r] + bv[1];
                float v2 = acc[mi][2][r] + bv[2];
                float v3 = acc[mi][3][r] + bv[3];
                size_t rb = (size_t)(rbase + r) * N + cbase;
                if (z == 2) {
                    o0[rb + 0 * 16 + l15] = f2bf(v0);
                    o0[rb + 1 * 16 + l15] = f2bf(v1);
                    o0[rb + 2 * 16 + l15] = f2bf(v2);
                    o0[rb + 3 * 16 + l15] = f2bf(v3);
                } else {
                    float s  = v0 + v1 + v2 + v3;
                    float sq = v0 * v0 + v1 * v1 + v2 * v2 + v3 * v3;
#pragma unroll
                    for (int m = 1; m < 16; m <<= 1) {
                        s  += __shfl_xor(s,  m);
                        sq += __shfl_xor(sq, m);
                    }
                    float mean = s * (1.0f / 64.0f);
                    float var  = sq * (1.0f / 64.0f) - mean * mean;
                    float inv  = rsqrtf(var + 1e-6f);
                    o0[rb + 0 * 16 + l15] = f2bf(((v0 - mean) * inv * sn[0] + bn[0]) * post);
                    o0[rb + 1 * 16 + l15] = f2bf(((v1 - mean) * inv * sn[1] + bn[1]) * post);
                    o0[rb + 2 * 16 + l15] = f2bf(((v2 - mean) * inv * sn[2] + bn[2]) * post);
                    o0[rb + 3 * 16 + l15] = f2bf(((v3 - mean) * inv * sn[3] + bn[3]) * post);
                }
            }
        }
    }
}

// ---------------- fused GeGLU FFN GEMM: 256-tile, 8-phase, counted vmcnt ----
// 512 threads, 8 waves (2M x 4N), wave tile 128x64, BK=64, LDS 128 KiB dbuf.
// B panel = interleaved W12I rows [256*bx, 256*bx+256): waves (w&1)==0 get x1
// cols, (w&1)==1 get x2 cols (same output cols, same rows). Epilogue: x2 waves
// write gelu(x2+b2) to LDS (reuse staging), x1 waves multiply + store H.
// Schedule: iter computes tiles t (buf0, ph1-4) and t+1 (buf1, ph5-8); one
// half-tile prefetch per phase into regions freed at an earlier phase's 2nd
// barrier; vmcnt(4) only at ph4/ph8 (keep 2 newest half-tiles in flight).
#define PH8(BUFI, S, ISSUE, TAIL)                                              \
  {                                                                            \
    const u16* LA = sm + (BUFI) * 32768;                                       \
    const u16* LB = LA + 16384;                                                \
    if ((S) == 0) {                                                            \
      _Pragma("unroll") for (int ni = 0; ni < 4; ++ni)                         \
      _Pragma("unroll") for (int kk = 0; kk < 2; ++kk)                         \
        bfr[ni][kk] = *(const bfrag*)&LB[(wcg + ni * 16 + l15) * 64            \
                                         + RS64(kk, quad, l15)];               \
    }                                                                          \
    bfrag a00 = *(const bfrag*)&LA[(wr128 + ((S)*2)     * 16 + l15) * 64 + RS64(0, quad, l15)]; \
    bfrag a01 = *(const bfrag*)&LA[(wr128 + ((S)*2)     * 16 + l15) * 64 + RS64(1, quad, l15)]; \
    bfrag a10 = *(const bfrag*)&LA[(wr128 + ((S)*2 + 1) * 16 + l15) * 64 + RS64(0, quad, l15)]; \
    bfrag a11 = *(const bfrag*)&LA[(wr128 + ((S)*2 + 1) * 16 + l15) * 64 + RS64(1, quad, l15)]; \
    ISSUE;                                                                     \
    asm volatile("" ::: "memory");                                             \
    __builtin_amdgcn_s_barrier();                                              \
    asm volatile("s_waitcnt lgkmcnt(0)" ::: "memory");                         \
    __builtin_amdgcn_s_setprio(1);                                             \
    _Pragma("unroll") for (int ni = 0; ni < 4; ++ni) {                         \
      acc[(S)*2][ni]     = __builtin_amdgcn_mfma_f32_16x16x32_bf16(a00, bfr[ni][0], acc[(S)*2][ni], 0, 0, 0);         \
      acc[(S)*2][ni]     = __builtin_amdgcn_mfma_f32_16x16x32_bf16(a01, bfr[ni][1], acc[(S)*2][ni], 0, 0, 0);         \
      acc[(S)*2 + 1][ni] = __builtin_amdgcn_mfma_f32_16x16x32_bf16(a10, bfr[ni][0], acc[(S)*2 + 1][ni], 0, 0, 0);     \
      acc[(S)*2 + 1][ni] = __builtin_amdgcn_mfma_f32_16x16x32_bf16(a11, bfr[ni][1], acc[(S)*2 + 1][ni], 0, 0, 0);     \
    }                                                                          \
    __builtin_amdgcn_s_setprio(0);                                             \
    TAIL;                                                                      \
    asm volatile("" ::: "memory");                                             \
    __builtin_amdgcn_s_barrier();                                              \
    asm volatile("" ::: "memory");                                             \
  }

__global__ __launch_bounds__(512, 2) void gemm_w12_8ph(
        const u16* __restrict__ A, const u16* __restrict__ BI,
        const float* __restrict__ b1, const float* __restrict__ b2,
        u16* __restrict__ H) {
    extern __shared__ __align__(16) u16 sm[];   // 128 KiB: [buf][A|B][256*64]
    int tid = threadIdx.x, w = tid >> 6, lane = tid & 63;
    int quad = lane >> 4, l15 = lane & 15;
    int row0  = blockIdx.y * 256;
    int nrow0 = blockIdx.x * 256;     // interleaved W12I row base
    int wr128 = (w >> 2) * 128, wcg = (w & 3) * 64;
    int strow = w * 8 + (lane >> 3);
    int swz8  = ((lane & 7) ^ ((lane >> 3) & 7)) * 8;
    int lw8   = w * 8;                // wave-uniform LDS row base

    const u16* gA = A  + (size_t)(row0  + strow) * 1024 + swz8;
    const u16* gB = BI + (size_t)(nrow0 + strow) * 1024 + swz8;

    f32x4 acc[8][4] = {};
    bfrag bfr[4][2];

    // one half-tile (128 rows x 64 k) = 2 x g2l16 per thread (512 threads)
    auto stage = [&](int bufi, int isB, int half, int t) {
        const u16* g = (isB ? gB : gA) + (size_t)half * 128 * 1024 + t * 64;
        u16* l = sm + bufi * 32768 + isB * 16384 + (half * 128 + lw8) * 64;
        g2l16(g, l);
        g2l16(g + 64 * 1024, l + 64 * 64);
    };

    // prologue: B(t0) both halves, A(t0) both halves, B(t1) both halves
    stage(0, 1, 0, 0); stage(0, 1, 1, 0);
    stage(0, 0, 0, 0); stage(0, 0, 1, 0);
    stage(1, 1, 0, 1); stage(1, 1, 1, 1);
    asm volatile("s_waitcnt vmcnt(4)" ::: "memory");   // t0 landed; B(t1) in flight
    __builtin_amdgcn_s_barrier();
    asm volatile("" ::: "memory");

#pragma unroll 1
    for (int i = 0; i < 8; ++i) {
        int t = 2 * i;
        bool more = (i < 7);
        PH8(0, 0, { stage(1, 0, 0, t + 1); }, {});                       // ph1
        PH8(0, 1, { stage(1, 0, 1, t + 1); }, {});                       // ph2
        PH8(0, 2, { if (more) stage(0, 1, 0, t + 2); }, {});             // ph3
        PH8(0, 3, { if (more) stage(0, 1, 1, t + 2); },                  // ph4
                  { if (more) asm volatile("s_waitcnt vmcnt(4)" ::: "memory");
                    else      asm volatile("s_waitcnt vmcnt(0)" ::: "memory"); });
        PH8(1, 0, { if (more) stage(0, 0, 0, t + 2); }, {});             // ph5
        PH8(1, 1, { if (more) stage(0, 0, 1, t + 2); }, {});             // ph6
        PH8(1, 2, { if (more) stage(1, 1, 0, t + 3); }, {});             // ph7
        PH8(1, 3, { if (more) stage(1, 1, 1, t + 3); },                  // ph8
                  { if (more) asm volatile("s_waitcnt vmcnt(4)" ::: "memory"); });
    }

    // ---- epilogue: pair exchange via LDS (staging buffers are dead) --------
    int c0 = blockIdx.x * 128 + ((w & 3) >> 1) * 64;
    const float* bp = (w & 1) ? b2 : b1;
    float bvv[4];
#pragma unroll
    for (int ni = 0; ni < 4; ++ni) bvv[ni] = bp[c0 + ni * 16 + l15];

    float* xg = (float*)(void*)sm + (w >> 1) * (128 * 64);
    if (w & 1) {       // x2 waves: gelu(x2 + b2) -> LDS (2-way swizzled: free)
#pragma unroll
        for (int mi = 0; mi < 8; ++mi)
#pragma unroll
        for (int ni = 0; ni < 4; ++ni) {
            int lc = (ni * 16 + l15) ^ (quad << 4);
#pragma unroll
            for (int r = 0; r < 4; ++r)
                xg[(mi * 16 + quad * 4 + r) * 64 + lc] =
                    gelu_tanh(acc[mi][ni][r] + bvv[ni]);
        }
    }
    asm volatile("" ::: "memory");
    __builtin_amdgcn_s_barrier();
    asm volatile("" ::: "memory");
    if (!(w & 1)) {    // x1 waves: (x1 + b1) * g -> H
#pragma unroll
        for (int mi = 0; mi < 8; ++mi) {
            int gr = row0 + wr128 + mi * 16 + quad * 4;
#pragma unroll
            for (int r = 0; r < 4; ++r)
#pragma unroll
            for (int ni = 0; ni < 4; ++ni) {
                float g = xg[(mi * 16 + quad * 4 + r) * 64
                             + ((ni * 16 + l15) ^ (quad << 4))];
                H[(size_t)(gr + r) * 4096 + c0 + ni * 16 + l15] =
                    f2bf((acc[mi][ni][r] + bvv[ni]) * g);
            }
        }
    }
}

// ---- fused Wo-reduce + residual + LN2 --------------------------------------
__global__ __launch_bounds__(256) void reduce_ln(const u16* __restrict__ p0,
                                                 const u16* __restrict__ p1,
                                                 const float* __restrict__ x,
                                                 const float* __restrict__ bo,
                                                 const float* __restrict__ s,
                                                 const float* __restrict__ b,
                                                 float* __restrict__ xmid,
                                                 u16* __restrict__ xn2) {
    int row = blockIdx.x, t = threadIdx.x;
    size_t i = (size_t)row * 1024 + t * 4;
    float4 xv = *(const float4*)&x[i];
    float4 bb = *(const float4*)&bo[t * 4];
    u16x4 a0 = *(const u16x4*)&p0[i];
    u16x4 a1 = *(const u16x4*)&p1[i];
    float4 v;
    v.x = xv.x + bb.x + bf2f(a0[0]) + bf2f(a1[0]);
    v.y = xv.y + bb.y + bf2f(a0[1]) + bf2f(a1[1]);
    v.z = xv.z + bb.z + bf2f(a0[2]) + bf2f(a1[2]);
    v.w = xv.w + bb.w + bf2f(a0[3]) + bf2f(a1[3]);
    *(float4*)&xmid[i] = v;
    float sum = v.x + v.y + v.z + v.w;
    float sq  = v.x * v.x + v.y * v.y + v.z * v.z + v.w * v.w;
#pragma unroll
    for (int off = 1; off < 64; off <<= 1) {
        sum += __shfl_xor(sum, off);
        sq  += __shfl_xor(sq,  off);
    }
    __shared__ float s1[4], s2[4];
    int wave = t >> 6;
    if ((t & 63) == 0) { s1[wave] = sum; s2[wave] = sq; }
    __syncthreads();
    sum = s1[0] + s1[1] + s1[2] + s1[3];
    sq  = s2[0] + s2[1] + s2[2] + s2[3];
    float mean = sum * (1.0f / 1024.0f);
    float var  = sq  * (1.0f / 1024.0f) - mean * mean;
    float inv  = rsqrtf(var + 1e-6f);
    float4 sc = ((const float4*)s)[t], lb = ((const float4*)b)[t];
    u16x4 o;
    o[0] = f2bf((v.x - mean) * inv * sc.x + lb.x);
    o[1] = f2bf((v.y - mean) * inv * sc.y + lb.y);
    o[2] = f2bf((v.z - mean) * inv * sc.z + lb.z);
    o[3] = f2bf((v.w - mean) * inv * sc.w + lb.w);
    *(u16x4*)&xn2[i] = o;
}

// ---------------- reduce: out = xmid + b3 + sum of 4 bf16 partials ----------
__global__ __launch_bounds__(256) void reduce4(const u16* __restrict__ p0,
                                               const u16* __restrict__ p1,
                                               const u16* __restrict__ p2,
                                               const u16* __restrict__ p3,
                                               const float* __restrict__ xmid,
                                               const float* __restrict__ b3,
                                               float* __restrict__ out) {
    size_t i = ((size_t)blockIdx.x * 256 + threadIdx.x) * 4;
    float4 xm = *(const float4*)&xmid[i];
    float4 bb = *(const float4*)&b3[i & 1023];
    u16x4 a0 = *(const u16x4*)&p0[i];
    u16x4 a1 = *(const u16x4*)&p1[i];
    u16x4 a2 = *(const u16x4*)&p2[i];
    u16x4 a3 = *(const u16x4*)&p3[i];
    float4 o;
    o.x = xm.x + bb.x + bf2f(a0[0]) + bf2f(a1[0]) + bf2f(a2[0]) + bf2f(a3[0]);
    o.y = xm.y + bb.y + bf2f(a0[1]) + bf2f(a1[1]) + bf2f(a2[1]) + bf2f(a3[1]);
    o.z = xm.z + bb.z + bf2f(a0[2]) + bf2f(a1[2]) + bf2f(a2[2]) + bf2f(a3[2]);
    o.w = xm.w + bb.w + bf2f(a0[3]) + bf2f(a1[3]) + bf2f(a2[3]) + bf2f(a3[3]);
    *(float4*)&out[i] = o;
}

// ---------------- Flash attention v2 ----------------------------------------
// grid (16 qt, 16 h, 4 b); 256 threads; 64-row Q tiles (16 rows/wave).
// Q frags direct from global; no-max softmax (|s|<=8 guaranteed by QK-norm:
// ||q*0.125||=1, ||k||=8 -> exp(s) <= e^8, fp32-safe); lane-local l partials
// reduced once in the epilogue. Vt staged seg=wave/key=lane (conflict-free
// ds_write_b16); Ps stride 68 u16 (quad bank-groups disjoint; b64-aligned).
#define LPK 72
#define LPV 72
#define LPP 68
__global__ __launch_bounds__(256, 4) void flash(const u16* __restrict__ qkv,
                                                u16* __restrict__ o) {
    int qt = blockIdx.x, h = blockIdx.y, b = blockIdx.z;
    int tid = threadIdx.x, wave = tid >> 6, lane = tid & 63;
    int quad = lane >> 4, l15 = lane & 15;

    __shared__ u16 Ks[64 * LPK];
    __shared__ u16 Vt[64 * LPV];   // [d][key]
    __shared__ u16 Ps[64 * LPP];

    // Q A-fragments straight from global (rows wave*16+l15, 16B contiguous)
    const u16* qrow = qkv + (size_t)(b * 1024 + qt * 64 + wave * 16 + l15) * 3072
                      + h * 64 + quad * 8;
    bfrag aq0 = *(const bfrag*)qrow;
    bfrag aq1 = *(const bfrag*)(qrow + 32);

    f32x4 accO[4] = {};
    float l_run[4] = {0.f, 0.f, 0.f, 0.f};

    for (int kt = 0; kt < 16; kt++) {
        __syncthreads();
        {   // K rows: row = tid>>2, seg = tid&3 (vector writes)
            int row = tid >> 2, seg = tid & 3;
            const u16* ksrc = qkv + (size_t)(b * 1024 + kt * 64 + row) * 3072
                              + 1024 + h * 64 + seg * 16;
            *(u16x8*)&Ks[row * LPK + seg * 16]     = *(const u16x8*)ksrc;
            *(u16x8*)&Ks[row * LPK + seg * 16 + 8] = *(const u16x8*)(ksrc + 8);
        }
        {   // V transposed: seg = wave, key = lane -> 64 consecutive u16/write
            const u16* vsrc = qkv + (size_t)(b * 1024 + kt * 64 + lane) * 3072
                              + 2048 + h * 64 + wave * 16;
            u16x8 v0 = *(const u16x8*)vsrc, v1 = *(const u16x8*)(vsrc + 8);
#pragma unroll
            for (int j = 0; j < 8; j++) Vt[(wave * 16 + j) * LPV + lane]     = v0[j];
#pragma unroll
            for (int j = 0; j < 8; j++) Vt[(wave * 16 + 8 + j) * LPV + lane] = v1[j];
        }
        __syncthreads();

        // S = Q x K^T over 64 keys
        f32x4 accS[4] = {};
#pragma unroll
        for (int ct = 0; ct < 4; ct++) {
            bfrag bk0 = *(const bfrag*)&Ks[(ct * 16 + l15) * LPK + quad * 8];
            bfrag bk1 = *(const bfrag*)&Ks[(ct * 16 + l15) * LPK + 32 + quad * 8];
            accS[ct] = __builtin_amdgcn_mfma_f32_16x16x32_bf16(aq0, bk0, accS[ct], 0, 0, 0);
            accS[ct] = __builtin_amdgcn_mfma_f32_16x16x32_bf16(aq1, bk1, accS[ct], 0, 0, 0);
        }

        // p = exp(s) (no max needed), lane-local l partial, write P
#pragma unroll
        for (int r = 0; r < 4; r++) {
            float p0 = __expf(accS[0][r]);
            float p1 = __expf(accS[1][r]);
            float p2 = __expf(accS[2][r]);
            float p3 = __expf(accS[3][r]);
            l_run[r] += (p0 + p1) + (p2 + p3);
            int pbase = (wave * 16 + quad * 4 + r) * LPP + l15;
            Ps[pbase + 0]  = f2bf(p0);
            Ps[pbase + 16] = f2bf(p1);
            Ps[pbase + 32] = f2bf(p2);
            Ps[pbase + 48] = f2bf(p3);
        }

        // O += P x V  (ap via two b64 reads; Vt rows give b128 B-frags)
#pragma unroll
        for (int kk = 0; kk < 2; kk++) {
            const u16* pp = &Ps[(wave * 16 + l15) * LPP + kk * 32 + quad * 8];
            u16x4 lo = *(const u16x4*)pp;
            u16x4 hi = *(const u16x4*)(pp + 4);
            u16x8 apu;
            apu[0] = lo[0]; apu[1] = lo[1]; apu[2] = lo[2]; apu[3] = lo[3];
            apu[4] = hi[0]; apu[5] = hi[1]; apu[6] = hi[2]; apu[7] = hi[3];
            bfrag ap = __builtin_bit_cast(bfrag, apu);
#pragma unroll
            for (int oc = 0; oc < 4; oc++) {
                bfrag bv = *(const bfrag*)&Vt[(oc * 16 + l15) * LPV + kk * 32 + quad * 8];
                accO[oc] = __builtin_amdgcn_mfma_f32_16x16x32_bf16(ap, bv, accO[oc], 0, 0, 0);
            }
        }
    }

    // epilogue: reduce l over the 16 row-lanes, normalize, store
#pragma unroll
    for (int r = 0; r < 4; r++) {
        float l = l_run[r];
#pragma unroll
        for (int m = 1; m < 16; m <<= 1) l += __shfl_xor(l, m);
        float linv = 1.0f / l;
        int srow = qt * 64 + wave * 16 + quad * 4 + r;
#pragma unroll
        for (int oc = 0; oc < 4; oc++)
            o[(size_t)(b * 1024 + srow) * 1024 + h * 64 + oc * 16 + l15] =
                f2bf(accO[oc][r] * linv);
    }
}

// ---------------------------------------------------------------------------
extern "C" void kernel_launch(void* const* d_in, const int* in_sizes, int n_in,
                              void* d_out, int out_size, void* d_ws, size_t ws_size,
                              hipStream_t stream) {
    const float* x     = (const float*)d_in[0];
    const float* ln1_s = (const float*)d_in[2];
    const float* ln1_b = (const float*)d_in[3];
    const float* Wq = (const float*)d_in[4];  const float* bq = (const float*)d_in[5];
    const float* Wk = (const float*)d_in[6];  const float* bk = (const float*)d_in[7];
    const float* Wv = (const float*)d_in[8];  const float* bv = (const float*)d_in[9];
    const float* qn_s = (const float*)d_in[10]; const float* qn_b = (const float*)d_in[11];
    const float* kn_s = (const float*)d_in[12]; const float* kn_b = (const float*)d_in[13];
    const float* Wo = (const float*)d_in[14]; const float* bo = (const float*)d_in[15];
    const float* ln2_s = (const float*)d_in[16]; const float* ln2_b = (const float*)d_in[17];
    const float* W1 = (const float*)d_in[18]; const float* b1 = (const float*)d_in[19];
    const float* W2 = (const float*)d_in[20]; const float* b2 = (const float*)d_in[21];
    const float* W3 = (const float*)d_in[22]; const float* b3 = (const float*)d_in[23];
    float* out = (float*)d_out;

    char* ws = (char*)d_ws;
    const size_t MB = (size_t)1 << 20;
    u16* WqkvT = (u16*)(ws + 0);         // 0..6    dead after QKV; then p0 @0
    u16* WoT   = (u16*)(ws + 6 * MB);    // 6..8    dead after Wo
    u16* W12T  = (u16*)(ws + 8 * MB);    // 8..24   dead after W12; then p1/p2
    u16* W3T   = (u16*)(ws + 24 * MB);   // 24..32  dead after splitk
    u16* xn1   = (u16*)(ws + 32 * MB);   // 32..40  dead after QKV
    u16* attn  = (u16*)(ws + 32 * MB);   //   reuse: dead after Wo-gemm
    u16* xn2   = (u16*)(ws + 32 * MB);   //   reuse: dead after W12
    u16* qkv   = (u16*)(ws + 40 * MB);   // 40..64  dead after flash
    float* xmid = (float*)(ws + 40 * MB);//   reuse: 40..56, alive until reduce4
    u16* p3    = (u16*)(ws + 56 * MB);   // 56..64
    u16* h     = (u16*)(ws + 64 * MB);   // 64..96  dead after splitk
    u16* wp0   = (u16*)(ws + 64 * MB);   // Wo partials: 64..72, 72..80
    u16* wp1   = (u16*)(ws + 72 * MB);   //   dead after reduce_ln (before h)
    u16* p0    = (u16*)(ws + 0);
    u16* p1    = (u16*)(ws + 8 * MB);
    u16* p2    = (u16*)(ws + 16 * MB);
    // peak = 96 MB

    wtln<<<20480, 256, 0, stream>>>(Wq, Wk, Wv, Wo, W1, W2, W3,
                                    WqkvT, WoT, W12T, W3T,
                                    x, ln1_s, ln1_b, xn1);

    // fused QKV + per-head QK-norm (BK=64)
    gemm64<4><<<dim3(24, 32, 1), 256, 0, stream>>>(
        xn1, WqkvT, bq, bk, bv, qn_s, qn_b, kn_s, kn_b,
        qkv, nullptr, nullptr, nullptr, 4096, 3072, 1024, 1024);

    flash<<<dim3(16, 16, 4), 256, 0, stream>>>(qkv, attn);

    // Wo split-K=2 partials (BK=64)
    gemm64<0><<<dim3(8, 32, 2), 256, 0, stream>>>(
        attn, WoT, nullptr, nullptr, nullptr, nullptr, nullptr, nullptr, nullptr,
        wp0, wp1, nullptr, nullptr, 4096, 1024, 1024, 512);

    // xmid = x + bo + wp0 + wp1; xn2 = LN2(xmid)
    reduce_ln<<<4096, 256, 0, stream>>>(wp0, wp1, x, bo, ln2_s, ln2_b, xmid, xn2);

    // fused GeGLU FFN: 256-tile 8-phase schedule, 128 KiB dynamic LDS
    gemm_w12_8ph<<<dim3(32, 16), 512, 131072, stream>>>(xn2, W12T, b1, b2, h);

    // W3 split-K=4 partials (BK=64)
    gemm64<0><<<dim3(8, 32, 4), 256, 0, stream>>>(
        h, W3T, nullptr, nullptr, nullptr, nullptr, nullptr, nullptr, nullptr,
        p0, p1, p2, p3, 4096, 1024, 4096, 1024);

    // out = xmid + b3 + sum(partials)
    reduce4<<<4096, 256, 0, stream>>>(p0, p1, p2, p3, xmid, b3, out);
}

// Round 2
// 414.620 us; speedup vs baseline: 1.0073x; 1.0073x over previous
//
#include <hip/hip_runtime.h>

typedef unsigned short u16;
typedef __bf16  bfrag  __attribute__((ext_vector_type(8)));   // MFMA A/B operand (4 VGPRs)
typedef float   f32x4  __attribute__((ext_vector_type(4)));   // MFMA C/D operand
typedef u16     u16x8  __attribute__((ext_vector_type(8)));
typedef u16     u16x4  __attribute__((ext_vector_type(4)));

__device__ __forceinline__ float bf2f(u16 u) {
    unsigned v = ((unsigned)u) << 16;
    return __builtin_bit_cast(float, v);
}
__device__ __forceinline__ u16 f2bf(float f) {   // round-to-nearest-even
    unsigned x = __builtin_bit_cast(unsigned, f);
    unsigned r = (x + 0x7fffu + ((x >> 16) & 1u)) >> 16;
    return (u16)r;
}
__device__ __forceinline__ void g2l16(const u16* g, u16* l) {
    // 16B per lane -> lds_base + lane*16 (wave-uniform LDS base)
    __builtin_amdgcn_global_load_lds((__attribute__((address_space(1))) void*)g,
                                     (__attribute__((address_space(3))) void*)l, 16, 0, 0);
}
__device__ __forceinline__ float gelu_tanh(float x) {
    // 0.5x(1+tanh(c)) == x * sigmoid(2c)
    float c = 1.5957691216057308f * (x + 0.044715f * x * x * x);
    return x * __frcp_rn(1.0f + __expf(-c));
}

// BK=64 LDS tiles: row = 128 B = 8 chunks of 16 B = exactly one 32-bank stripe.
// Swizzle phys_chunk = logical_chunk ^ (row & 7): conflict-free frag reads.
#define SW64(l)   (((((l) & 7) ^ (((l) >> 3) & 7))) * 8)
#define RS64(kk, quad, l15)  (((((kk) * 4 + (quad)) ^ ((l15) & 7))) * 8)

// ---------------- weight transposes + LN1 fused in ONE kernel ---------------
// W1/W2 emitted in INTERLEAVED layout W12I: 64-col groups alternate
// (W1 group q -> rows 128q..128q+63, W2 group q -> rows 128q+64..128q+127),
// so the 8-phase GeGLU GEMM reads a contiguous 256-row B panel per block.
__global__ __launch_bounds__(256) void wtln(
        const float* __restrict__ Wq, const float* __restrict__ Wk,
        const float* __restrict__ Wv, const float* __restrict__ Wo,
        const float* __restrict__ W1, const float* __restrict__ W2,
        const float* __restrict__ W3,
        u16* __restrict__ WqkvT, u16* __restrict__ WoT,
        u16* __restrict__ W12T, u16* __restrict__ W3T,
        const float* __restrict__ x, const float* __restrict__ ln1_s,
        const float* __restrict__ ln1_b, u16* __restrict__ xn1) {
    __shared__ float tile[32][33];
    int blk = blockIdx.x;
    if (blk >= 16384) {
        int row = blk - 16384, t = threadIdx.x;
        float4 v = ((const float4*)(x + (size_t)row * 1024))[t];
        float sum = v.x + v.y + v.z + v.w;
        float sq  = v.x * v.x + v.y * v.y + v.z * v.z + v.w * v.w;
#pragma unroll
        for (int off = 1; off < 64; off <<= 1) {
            sum += __shfl_xor(sum, off);
            sq  += __shfl_xor(sq,  off);
        }
        float* s1 = &tile[0][0];
        float* s2 = &tile[0][8];
        int wave = t >> 6;
        if ((t & 63) == 0) { s1[wave] = sum; s2[wave] = sq; }
        __syncthreads();
        sum = s1[0] + s1[1] + s1[2] + s1[3];
        sq  = s2[0] + s2[1] + s2[2] + s2[3];
        float mean = sum * (1.0f / 1024.0f);
        float var  = sq  * (1.0f / 1024.0f) - mean * mean;
        float inv  = rsqrtf(var + 1e-6f);
        float4 sc = ((const float4*)ln1_s)[t], bb = ((const float4*)ln1_b)[t];
        u16x4 o;
        o[0] = f2bf((v.x - mean) * inv * sc.x + bb.x);
        o[1] = f2bf((v.y - mean) * inv * sc.y + bb.y);
        o[2] = f2bf((v.z - mean) * inv * sc.z + bb.z);
        o[3] = f2bf((v.w - mean) * inv * sc.w + bb.w);
        *(u16x4*)&xn1[(size_t)row * 1024 + t * 4] = o;
        return;
    }
    const float* W; u16* Wt; int R, C, local; int ilv = -1;
    if (blk < 3072) {
        int w = blk >> 10; local = blk & 1023;
        W = (w == 0) ? Wq : (w == 1) ? Wk : Wv;
        Wt = WqkvT + (size_t)w * 1024 * 1024; R = 1024; C = 1024;
    } else if (blk < 4096) { W = Wo; Wt = WoT; R = 1024; C = 1024; local = blk - 3072; }
    else if (blk < 8192)   { W = W1; Wt = W12T; R = 1024; C = 4096; local = blk - 4096; ilv = 0; }
    else if (blk < 12288)  { W = W2; Wt = W12T; R = 1024; C = 4096; local = blk - 8192; ilv = 1; }
    else                   { W = W3; Wt = W3T; R = 4096; C = 1024; local = blk - 12288; }
    int tiles_x = C >> 5;
    int c0 = (local % tiles_x) * 32, r0 = (local / tiles_x) * 32;
    int tx = threadIdx.x & 31, ty = threadIdx.x >> 5;
#pragma unroll
    for (int i = 0; i < 32; i += 8)
        tile[ty + i][tx] = W[(size_t)(r0 + ty + i) * C + c0 + tx];
    __syncthreads();
#pragma unroll
    for (int i = 0; i < 32; i += 8) {
        int c = c0 + ty + i;
        int orow = (ilv < 0) ? c : ((c >> 6) * 128 + ilv * 64 + (c & 63));
        Wt[(size_t)orow * R + r0 + tx] = f2bf(tile[tx][ty + i]);
    }
}

// ---- gemm64: 4-wave 128x128 block tile, 64x64 wave tile, BK=64 -------------
// EPI 0: bf16 partial store to o[kz] (split-K) | 4: QKV + per-head LN.
template <int EPI>
__global__ __launch_bounds__(256, 3) void gemm64(const u16* __restrict__ A,
                                                 const u16* __restrict__ Bt,
                                                 const float* __restrict__ bias,
                                                 const float* __restrict__ bias2,
                                                 const float* __restrict__ bias3,
                                                 const float* __restrict__ qn_s,
                                                 const float* __restrict__ qn_b,
                                                 const float* __restrict__ kn_s,
                                                 const float* __restrict__ kn_b,
                                                 u16* __restrict__ o0,
                                                 u16* __restrict__ o1,
                                                 u16* __restrict__ o2,
                                                 u16* __restrict__ o3,
                                                 int M, int N, int K, int Klen) {
    __shared__ u16 As[128 * 64];
    __shared__ u16 Bs[128 * 64];
    int tid = threadIdx.x, wave = tid >> 6, lane = tid & 63;
    int quad = lane >> 4, l15 = lane & 15;
    int row0 = blockIdx.y * 128, col0 = blockIdx.x * 128;
    int kz = blockIdx.z;
    int wr = (wave >> 1) * 64, wc = (wave & 1) * 64;
    int swz = SW64(lane);

    f32x4 acc[4][4] = {};

    const u16* gA = A  + (size_t)(row0 + wave * 32 + (lane >> 3)) * K + kz * Klen + swz;
    const u16* gB = Bt + (size_t)(col0 + wave * 32 + (lane >> 3)) * K + kz * Klen + swz;
    u16* lA = &As[wave * 32 * 64];
    u16* lB = &Bs[wave * 32 * 64];

    for (int k0 = 0; k0 < Klen; k0 += 64) {
        __syncthreads();
#pragma unroll
        for (int j = 0; j < 4; j++) {
            g2l16(gA + k0 + j * 8 * K, lA + j * 8 * 64);
            g2l16(gB + k0 + j * 8 * K, lB + j * 8 * 64);
        }
        __syncthreads();
#pragma unroll
        for (int kk = 0; kk < 2; kk++) {
            int rs = RS64(kk, quad, l15);
            bfrag af[4], bf[4];
#pragma unroll
            for (int mi = 0; mi < 4; mi++)
                af[mi] = *(const bfrag*)&As[(wr + mi * 16 + l15) * 64 + rs];
#pragma unroll
            for (int ni = 0; ni < 4; ni++)
                bf[ni] = *(const bfrag*)&Bs[(wc + ni * 16 + l15) * 64 + rs];
#pragma unroll
            for (int mi = 0; mi < 4; mi++)
#pragma unroll
                for (int ni = 0; ni < 4; ni++)
                    acc[mi][ni] = __builtin_amdgcn_mfma_f32_16x16x32_bf16(
                        af[mi], bf[ni], acc[mi][ni], 0, 0, 0);
        }
    }

    if (EPI == 0) {
        u16* P = (kz == 0) ? o0 : (kz == 1) ? o1 : (kz == 2) ? o2 : o3;
#pragma unroll
        for (int mi = 0; mi < 4; mi++) {
            int rbase = row0 + wr + mi * 16 + quad * 4;
#pragma unroll
            for (int r = 0; r < 4; r++)
#pragma unroll
                for (int ni = 0; ni < 4; ni++)
                    P[(size_t)(rbase + r) * N + col0 + wc + ni * 16 + l15] =
                        f2bf(acc[mi][ni][r]);
        }
    } else {
        int cbase = col0 + wc;
        int z = cbase >> 10;              // 0=q, 1=k, 2=v
        int hd = (cbase >> 6) & 15;
        const float* bp = (z == 0) ? bias : (z == 1) ? bias2 : bias3;
        float post = (z == 0) ? 0.125f : 1.0f;
        float bv[4], sn[4], bn[4];
#pragma unroll
        for (int ni = 0; ni < 4; ni++)
            bv[ni] = bp[(cbase & 1023) + ni * 16 + l15];
        if (z < 2) {
            const float* ns = (z == 0) ? qn_s : kn_s;
            const float* nb = (z == 0) ? qn_b : kn_b;
#pragma unroll
            for (int ni = 0; ni < 4; ni++) {
                sn[ni] = ns[hd * 64 + ni * 16 + l15];
                bn[ni] = nb[hd * 64 + ni * 16 + l15];
            }
        }
#pragma unroll
        for (int mi = 0; mi < 4; mi++) {
            int rbase = row0 + wr + mi * 16 + quad * 4;
#pragma unroll
            for (int r = 0; r < 4; r++) {
                float v0 = acc[mi][0][r] + bv[0];
                float v1 = acc[mi][1][r] + bv[1];
                float v2 = acc[mi][2][r] + bv[2];
                float v3 = acc[mi][3][r] + bv[3];
                size_t rb = (size_t)(rbase + r) * N + cbase;
                if (z == 2) {
                    o0[rb + 0 * 16 + l15] = f2bf(v0);
                    o0[rb + 1 * 16 + l15] = f2bf(v1);
                    o0[rb + 2 * 16 + l15] = f2bf(v2);
                    o0[rb + 3 * 16 + l15] = f2bf(v3);
                } else {
                    float s  = v0 + v1 + v2 + v3;
                    float sq = v0 * v0 + v1 * v1 + v2 * v2 + v3 * v3;
#pragma unroll
                    for (int m = 1; m < 16; m <<= 1) {
                        s  += __shfl_xor(s,  m);
                        sq += __shfl_xor(sq, m);
                    }
                    float mean = s * (1.0f / 64.0f);
                    float var  = sq * (1.0f / 64.0f) - mean * mean;
                    float inv  = rsqrtf(var + 1e-6f);
                    o0[rb + 0 * 16 + l15] = f2bf(((v0 - mean) * inv * sn[0] + bn[0]) * post);
                    o0[rb + 1 * 16 + l15] = f2bf(((v1 - mean) * inv * sn[1] + bn[1]) * post);
                    o0[rb + 2 * 16 + l15] = f2bf(((v2 - mean) * inv * sn[2] + bn[2]) * post);
                    o0[rb + 3 * 16 + l15] = f2bf(((v3 - mean) * inv * sn[3] + bn[3]) * post);
                }
            }
        }
    }
}

// ---------------- fused GeGLU FFN GEMM: 256-tile, 8-phase, deep pipeline ----
// 512 threads, 8 waves (2M x 4N), wave tile 128x64, BK=64, LDS 128 KiB dbuf.
// Strip-granular staging: B-frags consumed only at S==0 (register-cached), so
// B LDS is free for 7 phases; A strip s last read at phase s. Schedule stages
// 2x8KB strips/phase with min 4-phase (typ 5-6) latency cover:
//   ph0: A23(t+1) | ph1: B01(t+2) | ph2: B23(t+2) | ph3: A01(t+2)
//   ph4: A23(t+2) | ph5: B01(t+3) | ph6: B23(t+3) | ph7: A01(t+3)
// FIFO-verified waits: vmcnt(10) @ph1/ph5 tails, vmcnt(8) @ph3/ph7 tails
// (never 0 mid-loop). XCD-chunked bx-major swizzle keeps the 4 B panels an
// XCD touches L2-resident (2 MB < 4 MB).
#define VMC(n)  asm volatile("s_waitcnt vmcnt(" #n ")" ::: "memory")

#define PH8(BUFI, S, ISSUE, TAIL)                                              \
  {                                                                            \
    const u16* LA = sm + (BUFI) * 32768;                                       \
    const u16* LB = LA + 16384;                                                \
    if ((S) == 0) {                                                            \
      _Pragma("unroll") for (int ni = 0; ni < 4; ++ni)                         \
      _Pragma("unroll") for (int kk = 0; kk < 2; ++kk)                         \
        bfr[ni][kk] = *(const bfrag*)&LB[(wcg + ni * 16 + l15) * 64            \
                                         + RS64(kk, quad, l15)];               \
    }                                                                          \
    bfrag a00 = *(const bfrag*)&LA[(wr128 + ((S)*2)     * 16 + l15) * 64 + RS64(0, quad, l15)]; \
    bfrag a01 = *(const bfrag*)&LA[(wr128 + ((S)*2)     * 16 + l15) * 64 + RS64(1, quad, l15)]; \
    bfrag a10 = *(const bfrag*)&LA[(wr128 + ((S)*2 + 1) * 16 + l15) * 64 + RS64(0, quad, l15)]; \
    bfrag a11 = *(const bfrag*)&LA[(wr128 + ((S)*2 + 1) * 16 + l15) * 64 + RS64(1, quad, l15)]; \
    ISSUE;                                                                     \
    asm volatile("" ::: "memory");                                             \
    __builtin_amdgcn_s_barrier();                                              \
    asm volatile("s_waitcnt lgkmcnt(0)" ::: "memory");                         \
    __builtin_amdgcn_s_setprio(1);                                             \
    _Pragma("unroll") for (int ni = 0; ni < 4; ++ni) {                         \
      acc[(S)*2][ni]     = __builtin_amdgcn_mfma_f32_16x16x32_bf16(a00, bfr[ni][0], acc[(S)*2][ni], 0, 0, 0);         \
      acc[(S)*2][ni]     = __builtin_amdgcn_mfma_f32_16x16x32_bf16(a01, bfr[ni][1], acc[(S)*2][ni], 0, 0, 0);         \
      acc[(S)*2 + 1][ni] = __builtin_amdgcn_mfma_f32_16x16x32_bf16(a10, bfr[ni][0], acc[(S)*2 + 1][ni], 0, 0, 0);     \
      acc[(S)*2 + 1][ni] = __builtin_amdgcn_mfma_f32_16x16x32_bf16(a11, bfr[ni][1], acc[(S)*2 + 1][ni], 0, 0, 0);     \
    }                                                                          \
    __builtin_amdgcn_s_setprio(0);                                             \
    TAIL;                                                                      \
    asm volatile("" ::: "memory");                                             \
    __builtin_amdgcn_s_barrier();                                              \
    asm volatile("" ::: "memory");                                             \
  }

__global__ __launch_bounds__(512, 2) void gemm_w12_8ph(
        const u16* __restrict__ A, const u16* __restrict__ BI,
        const float* __restrict__ b1, const float* __restrict__ b2,
        u16* __restrict__ H) {
    extern __shared__ __align__(16) u16 sm[];   // 128 KiB: [buf][A|B][256*64]
    int tid = threadIdx.x, w = tid >> 6, lane = tid & 63;
    int quad = lane >> 4, l15 = lane & 15;

    // XCD-chunked bijective swizzle (512 blocks, 8 XCDs): XCD k gets orig ids
    // [64k, 64k+64) = bx in [4k,4k+4) x all by  ->  B working set 2 MB (L2).
    int raw  = blockIdx.x;
    int orig = (raw & 7) * 64 + (raw >> 3);
    int bx = orig >> 4, by = orig & 15;
    int row0  = by * 256;
    int nrow0 = bx * 256;     // interleaved W12I row base

    int wr128 = (w >> 2) * 128, wcg = (w & 3) * 64;
    int swz8  = ((lane & 7) ^ ((lane >> 3) & 7)) * 8;

    // A-strip s (s=0..3): global rows row0 + {half*128 + s*32 + (w&3)*8 + lr}
    int rA = (w >> 2) * 128 + (w & 3) * 8 + (lane >> 3);
    const u16* gA2 = A + (size_t)(row0 + rA) * 1024 + swz8;
    int aRowW = (w >> 2) * 128 + (w & 3) * 8;      // wave-uniform LDS row base
    // B-strip b (b=0..3): rows nrow0 + {b*64 + w*8 + lr}
    int rB = w * 8 + (lane >> 3);
    const u16* gB2 = BI + (size_t)(nrow0 + rB) * 1024 + swz8;
    int bRowW = w * 8;

    f32x4 acc[8][4] = {};
    bfrag bfr[4][2];

    auto stageA = [&](int bufi, int s, int t) {   // 8 KB: 1 g2l16/thread
        g2l16(gA2 + (size_t)s * 32 * 1024 + t * 64,
              sm + bufi * 32768 + (aRowW + s * 32) * 64);
    };
    auto stageB = [&](int bufi, int b, int t) {
        g2l16(gB2 + (size_t)b * 64 * 1024 + t * 64,
              sm + bufi * 32768 + 16384 + (bRowW + b * 64) * 64);
    };

    // prologue: tile0 complete + tile1 {B all, A01}; leave 8 in flight
    stageB(0, 0, 0); stageB(0, 1, 0); stageB(0, 2, 0); stageB(0, 3, 0);
    stageA(0, 0, 0); stageA(0, 1, 0); stageA(0, 2, 0); stageA(0, 3, 0);
    stageB(1, 0, 1); stageB(1, 1, 1); stageB(1, 2, 1); stageB(1, 3, 1);
    stageA(1, 0, 1); stageA(1, 1, 1);
    VMC(8);                    // tile0 landed; [A23(0), B(1)x4, A01(1)] in flight
    __builtin_amdgcn_s_barrier();
    asm volatile("" ::: "memory");

#pragma unroll 1
    for (int i = 0; i < 8; ++i) {
        int t1 = 2 * i + 1, t2 = 2 * i + 2, t3 = 2 * i + 3;
        bool more = (i < 7);
        PH8(0, 0, { stageA(1, 2, t1); stageA(1, 3, t1); }, {});
        PH8(0, 1, { if (more) { stageB(0, 0, t2); stageB(0, 1, t2); } },
                  { if (more) VMC(10); else VMC(8); });
        PH8(0, 2, { if (more) { stageB(0, 2, t2); stageB(0, 3, t2); } }, {});
        PH8(0, 3, { if (more) { stageA(0, 0, t2); stageA(0, 1, t2); } },
                  { if (more) VMC(8); else VMC(2); });
        PH8(1, 0, { if (more) { stageA(0, 2, t2); stageA(0, 3, t2); } }, {});
        PH8(1, 1, { if (more) { stageB(1, 0, t3); stageB(1, 1, t3); } },
                  { if (more) VMC(10); else VMC(0); });
        PH8(1, 2, { if (more) { stageB(1, 2, t3); stageB(1, 3, t3); } }, {});
        PH8(1, 3, { if (more) { stageA(1, 0, t3); stageA(1, 1, t3); } },
                  { if (more) VMC(8); });
    }

    // ---- epilogue: pair exchange via LDS (staging buffers are dead) --------
    int c0 = bx * 128 + ((w & 3) >> 1) * 64;
    const float* bp = (w & 1) ? b2 : b1;
    float bvv[4];
#pragma unroll
    for (int ni = 0; ni < 4; ++ni) bvv[ni] = bp[c0 + ni * 16 + l15];

    float* xg = (float*)(void*)sm + (w >> 1) * (128 * 64);
    if (w & 1) {       // x2 waves: gelu(x2 + b2) -> LDS (2-way swizzled: free)
#pragma unroll
        for (int mi = 0; mi < 8; ++mi)
#pragma unroll
        for (int ni = 0; ni < 4; ++ni) {
            int lc = (ni * 16 + l15) ^ (quad << 4);
#pragma unroll
            for (int r = 0; r < 4; ++r)
                xg[(mi * 16 + quad * 4 + r) * 64 + lc] =
                    gelu_tanh(acc[mi][ni][r] + bvv[ni]);
        }
    }
    asm volatile("" ::: "memory");
    __builtin_amdgcn_s_barrier();
    asm volatile("" ::: "memory");
    if (!(w & 1)) {    // x1 waves: (x1 + b1) * g -> H
#pragma unroll
        for (int mi = 0; mi < 8; ++mi) {
            int gr = row0 + wr128 + mi * 16 + quad * 4;
#pragma unroll
            for (int r = 0; r < 4; ++r)
#pragma unroll
            for (int ni = 0; ni < 4; ++ni) {
                float g = xg[(mi * 16 + quad * 4 + r) * 64
                             + ((ni * 16 + l15) ^ (quad << 4))];
                H[(size_t)(gr + r) * 4096 + c0 + ni * 16 + l15] =
                    f2bf((acc[mi][ni][r] + bvv[ni]) * g);
            }
        }
    }
}

// ---- fused Wo-reduce + residual + LN2 --------------------------------------
__global__ __launch_bounds__(256) void reduce_ln(const u16* __restrict__ p0,
                                                 const u16* __restrict__ p1,
                                                 const float* __restrict__ x,
                                                 const float* __restrict__ bo,
                                                 const float* __restrict__ s,
                                                 const float* __restrict__ b,
                                                 float* __restrict__ xmid,
                                                 u16* __restrict__ xn2) {
    int row = blockIdx.x, t = threadIdx.x;
    size_t i = (size_t)row * 1024 + t * 4;
    float4 xv = *(const float4*)&x[i];
    float4 bb = *(const float4*)&bo[t * 4];
    u16x4 a0 = *(const u16x4*)&p0[i];
    u16x4 a1 = *(const u16x4*)&p1[i];
    float4 v;
    v.x = xv.x + bb.x + bf2f(a0[0]) + bf2f(a1[0]);
    v.y = xv.y + bb.y + bf2f(a0[1]) + bf2f(a1[1]);
    v.z = xv.z + bb.z + bf2f(a0[2]) + bf2f(a1[2]);
    v.w = xv.w + bb.w + bf2f(a0[3]) + bf2f(a1[3]);
    *(float4*)&xmid[i] = v;
    float sum = v.x + v.y + v.z + v.w;
    float sq  = v.x * v.x + v.y * v.y + v.z * v.z + v.w * v.w;
#pragma unroll
    for (int off = 1; off < 64; off <<= 1) {
        sum += __shfl_xor(sum, off);
        sq  += __shfl_xor(sq,  off);
    }
    __shared__ float s1[4], s2[4];
    int wave = t >> 6;
    if ((t & 63) == 0) { s1[wave] = sum; s2[wave] = sq; }
    __syncthreads();
    sum = s1[0] + s1[1] + s1[2] + s1[3];
    sq  = s2[0] + s2[1] + s2[2] + s2[3];
    float mean = sum * (1.0f / 1024.0f);
    float var  = sq  * (1.0f / 1024.0f) - mean * mean;
    float inv  = rsqrtf(var + 1e-6f);
    float4 sc = ((const float4*)s)[t], lb = ((const float4*)b)[t];
    u16x4 o;
    o[0] = f2bf((v.x - mean) * inv * sc.x + lb.x);
    o[1] = f2bf((v.y - mean) * inv * sc.y + lb.y);
    o[2] = f2bf((v.z - mean) * inv * sc.z + lb.z);
    o[3] = f2bf((v.w - mean) * inv * sc.w + lb.w);
    *(u16x4*)&xn2[i] = o;
}

// ---------------- reduce: out = xmid + b3 + sum of 4 bf16 partials ----------
__global__ __launch_bounds__(256) void reduce4(const u16* __restrict__ p0,
                                               const u16* __restrict__ p1,
                                               const u16* __restrict__ p2,
                                               const u16* __restrict__ p3,
                                               const float* __restrict__ xmid,
                                               const float* __restrict__ b3,
                                               float* __restrict__ out) {
    size_t i = ((size_t)blockIdx.x * 256 + threadIdx.x) * 4;
    float4 xm = *(const float4*)&xmid[i];
    float4 bb = *(const float4*)&b3[i & 1023];
    u16x4 a0 = *(const u16x4*)&p0[i];
    u16x4 a1 = *(const u16x4*)&p1[i];
    u16x4 a2 = *(const u16x4*)&p2[i];
    u16x4 a3 = *(const u16x4*)&p3[i];
    float4 o;
    o.x = xm.x + bb.x + bf2f(a0[0]) + bf2f(a1[0]) + bf2f(a2[0]) + bf2f(a3[0]);
    o.y = xm.y + bb.y + bf2f(a0[1]) + bf2f(a1[1]) + bf2f(a2[1]) + bf2f(a3[1]);
    o.z = xm.z + bb.z + bf2f(a0[2]) + bf2f(a1[2]) + bf2f(a2[2]) + bf2f(a3[2]);
    o.w = xm.w + bb.w + bf2f(a0[3]) + bf2f(a1[3]) + bf2f(a2[3]) + bf2f(a3[3]);
    *(float4*)&out[i] = o;
}

// ---------------- Flash attention v2 ----------------------------------------
// grid (16 qt, 16 h, 4 b); 256 threads; 64-row Q tiles (16 rows/wave).
// Q frags direct from global; no-max softmax (|s|<=8 guaranteed by QK-norm:
// ||q*0.125||=1, ||k||=8 -> exp(s) <= e^8, fp32-safe); lane-local l partials
// reduced once in the epilogue. Vt staged seg=wave/key=lane (conflict-free
// ds_write_b16); Ps stride 68 u16 (quad bank-groups disjoint; b64-aligned).
#define LPK 72
#define LPV 72
#define LPP 68
__global__ __launch_bounds__(256, 4) void flash(const u16* __restrict__ qkv,
                                                u16* __restrict__ o) {
    int qt = blockIdx.x, h = blockIdx.y, b = blockIdx.z;
    int tid = threadIdx.x, wave = tid >> 6, lane = tid & 63;
    int quad = lane >> 4, l15 = lane & 15;

    __shared__ u16 Ks[64 * LPK];
    __shared__ u16 Vt[64 * LPV];   // [d][key]
    __shared__ u16 Ps[64 * LPP];

    // Q A-fragments straight from global (rows wave*16+l15, 16B contiguous)
    const u16* qrow = qkv + (size_t)(b * 1024 + qt * 64 + wave * 16 + l15) * 3072
                      + h * 64 + quad * 8;
    bfrag aq0 = *(const bfrag*)qrow;
    bfrag aq1 = *(const bfrag*)(qrow + 32);

    f32x4 accO[4] = {};
    float l_run[4] = {0.f, 0.f, 0.f, 0.f};

    for (int kt = 0; kt < 16; kt++) {
        __syncthreads();
        {   // K rows: row = tid>>2, seg = tid&3 (vector writes)
            int row = tid >> 2, seg = tid & 3;
            const u16* ksrc = qkv + (size_t)(b * 1024 + kt * 64 + row) * 3072
                              + 1024 + h * 64 + seg * 16;
            *(u16x8*)&Ks[row * LPK + seg * 16]     = *(const u16x8*)ksrc;
            *(u16x8*)&Ks[row * LPK + seg * 16 + 8] = *(const u16x8*)(ksrc + 8);
        }
        {   // V transposed: seg = wave, key = lane -> 64 consecutive u16/write
            const u16* vsrc = qkv + (size_t)(b * 1024 + kt * 64 + lane) * 3072
                              + 2048 + h * 64 + wave * 16;
            u16x8 v0 = *(const u16x8*)vsrc, v1 = *(const u16x8*)(vsrc + 8);
#pragma unroll
            for (int j = 0; j < 8; j++) Vt[(wave * 16 + j) * LPV + lane]     = v0[j];
#pragma unroll
            for (int j = 0; j < 8; j++) Vt[(wave * 16 + 8 + j) * LPV + lane] = v1[j];
        }
        __syncthreads();

        // S = Q x K^T over 64 keys
        f32x4 accS[4] = {};
#pragma unroll
        for (int ct = 0; ct < 4; ct++) {
            bfrag bk0 = *(const bfrag*)&Ks[(ct * 16 + l15) * LPK + quad * 8];
            bfrag bk1 = *(const bfrag*)&Ks[(ct * 16 + l15) * LPK + 32 + quad * 8];
            accS[ct] = __builtin_amdgcn_mfma_f32_16x16x32_bf16(aq0, bk0, accS[ct], 0, 0, 0);
            accS[ct] = __builtin_amdgcn_mfma_f32_16x16x32_bf16(aq1, bk1, accS[ct], 0, 0, 0);
        }

        // p = exp(s) (no max needed), lane-local l partial, write P
#pragma unroll
        for (int r = 0; r < 4; r++) {
            float p0 = __expf(accS[0][r]);
            float p1 = __expf(accS[1][r]);
            float p2 = __expf(accS[2][r]);
            float p3 = __expf(accS[3][r]);
            l_run[r] += (p0 + p1) + (p2 + p3);
            int pbase = (wave * 16 + quad * 4 + r) * LPP + l15;
            Ps[pbase + 0]  = f2bf(p0);
            Ps[pbase + 16] = f2bf(p1);
            Ps[pbase + 32] = f2bf(p2);
            Ps[pbase + 48] = f2bf(p3);
        }

        // O += P x V  (ap via two b64 reads; Vt rows give b128 B-frags)
#pragma unroll
        for (int kk = 0; kk < 2; kk++) {
            const u16* pp = &Ps[(wave * 16 + l15) * LPP + kk * 32 + quad * 8];
            u16x4 lo = *(const u16x4*)pp;
            u16x4 hi = *(const u16x4*)(pp + 4);
            u16x8 apu;
            apu[0] = lo[0]; apu[1] = lo[1]; apu[2] = lo[2]; apu[3] = lo[3];
            apu[4] = hi[0]; apu[5] = hi[1]; apu[6] = hi[2]; apu[7] = hi[3];
            bfrag ap = __builtin_bit_cast(bfrag, apu);
#pragma unroll
            for (int oc = 0; oc < 4; oc++) {
                bfrag bv = *(const bfrag*)&Vt[(oc * 16 + l15) * LPV + kk * 32 + quad * 8];
                accO[oc] = __builtin_amdgcn_mfma_f32_16x16x32_bf16(ap, bv, accO[oc], 0, 0, 0);
            }
        }
    }

    // epilogue: reduce l over the 16 row-lanes, normalize, store
#pragma unroll
    for (int r = 0; r < 4; r++) {
        float l = l_run[r];
#pragma unroll
        for (int m = 1; m < 16; m <<= 1) l += __shfl_xor(l, m);
        float linv = 1.0f / l;
        int srow = qt * 64 + wave * 16 + quad * 4 + r;
#pragma unroll
        for (int oc = 0; oc < 4; oc++)
            o[(size_t)(b * 1024 + srow) * 1024 + h * 64 + oc * 16 + l15] =
                f2bf(accO[oc][r] * linv);
    }
}

// ---------------------------------------------------------------------------
extern "C" void kernel_launch(void* const* d_in, const int* in_sizes, int n_in,
                              void* d_out, int out_size, void* d_ws, size_t ws_size,
                              hipStream_t stream) {
    const float* x     = (const float*)d_in[0];
    const float* ln1_s = (const float*)d_in[2];
    const float* ln1_b = (const float*)d_in[3];
    const float* Wq = (const float*)d_in[4];  const float* bq = (const float*)d_in[5];
    const float* Wk = (const float*)d_in[6];  const float* bk = (const float*)d_in[7];
    const float* Wv = (const float*)d_in[8];  const float* bv = (const float*)d_in[9];
    const float* qn_s = (const float*)d_in[10]; const float* qn_b = (const float*)d_in[11];
    const float* kn_s = (const float*)d_in[12]; const float* kn_b = (const float*)d_in[13];
    const float* Wo = (const float*)d_in[14]; const float* bo = (const float*)d_in[15];
    const float* ln2_s = (const float*)d_in[16]; const float* ln2_b = (const float*)d_in[17];
    const float* W1 = (const float*)d_in[18]; const float* b1 = (const float*)d_in[19];
    const float* W2 = (const float*)d_in[20]; const float* b2 = (const float*)d_in[21];
    const float* W3 = (const float*)d_in[22]; const float* b3 = (const float*)d_in[23];
    float* out = (float*)d_out;

    char* ws = (char*)d_ws;
    const size_t MB = (size_t)1 << 20;
    u16* WqkvT = (u16*)(ws + 0);         // 0..6    dead after QKV; then p0 @0
    u16* WoT   = (u16*)(ws + 6 * MB);    // 6..8    dead after Wo
    u16* W12T  = (u16*)(ws + 8 * MB);    // 8..24   dead after W12; then p1/p2
    u16* W3T   = (u16*)(ws + 24 * MB);   // 24..32  dead after splitk
    u16* xn1   = (u16*)(ws + 32 * MB);   // 32..40  dead after QKV
    u16* attn  = (u16*)(ws + 32 * MB);   //   reuse: dead after Wo-gemm
    u16* xn2   = (u16*)(ws + 32 * MB);   //   reuse: dead after W12
    u16* qkv   = (u16*)(ws + 40 * MB);   // 40..64  dead after flash
    float* xmid = (float*)(ws + 40 * MB);//   reuse: 40..56, alive until reduce4
    u16* p3    = (u16*)(ws + 56 * MB);   // 56..64
    u16* h     = (u16*)(ws + 64 * MB);   // 64..96  dead after splitk
    u16* wp0   = (u16*)(ws + 64 * MB);   // Wo partials: 64..72, 72..80
    u16* wp1   = (u16*)(ws + 72 * MB);   //   dead after reduce_ln (before h)
    u16* p0    = (u16*)(ws + 0);
    u16* p1    = (u16*)(ws + 8 * MB);
    u16* p2    = (u16*)(ws + 16 * MB);
    // peak = 96 MB

    wtln<<<20480, 256, 0, stream>>>(Wq, Wk, Wv, Wo, W1, W2, W3,
                                    WqkvT, WoT, W12T, W3T,
                                    x, ln1_s, ln1_b, xn1);

    // fused QKV + per-head QK-norm (BK=64)
    gemm64<4><<<dim3(24, 32, 1), 256, 0, stream>>>(
        xn1, WqkvT, bq, bk, bv, qn_s, qn_b, kn_s, kn_b,
        qkv, nullptr, nullptr, nullptr, 4096, 3072, 1024, 1024);

    flash<<<dim3(16, 16, 4), 256, 0, stream>>>(qkv, attn);

    // Wo split-K=2 partials (BK=64)
    gemm64<0><<<dim3(8, 32, 2), 256, 0, stream>>>(
        attn, WoT, nullptr, nullptr, nullptr, nullptr, nullptr, nullptr, nullptr,
        wp0, wp1, nullptr, nullptr, 4096, 1024, 1024, 512);

    // xmid = x + bo + wp0 + wp1; xn2 = LN2(xmid)
    reduce_ln<<<4096, 256, 0, stream>>>(wp0, wp1, x, bo, ln2_s, ln2_b, xmid, xn2);

    // fused GeGLU FFN: 256-tile 8-phase deep-pipelined schedule, 128 KiB LDS
    gemm_w12_8ph<<<dim3(512, 1), 512, 131072, stream>>>(xn2, W12T, b1, b2, h);

    // W3 split-K=4 partials (BK=64)
    gemm64<0><<<dim3(8, 32, 4), 256, 0, stream>>>(
        h, W3T, nullptr, nullptr, nullptr, nullptr, nullptr, nullptr, nullptr,
        p0, p1, p2, p3, 4096, 1024, 4096, 1024);

    // out = xmid + b3 + sum(partials)
    reduce4<<<4096, 256, 0, stream>>>(p0, p1, p2, p3, xmid, b3, out);
}

// Round 3
// 398.027 us; speedup vs baseline: 1.0492x; 1.0417x over previous
//
#include <hip/hip_runtime.h>

typedef unsigned short u16;
typedef __bf16  bfrag  __attribute__((ext_vector_type(8)));   // MFMA A/B operand (4 VGPRs)
typedef float   f32x4  __attribute__((ext_vector_type(4)));   // MFMA C/D operand
typedef u16     u16x8  __attribute__((ext_vector_type(8)));
typedef u16     u16x4  __attribute__((ext_vector_type(4)));

__device__ __forceinline__ float bf2f(u16 u) {
    unsigned v = ((unsigned)u) << 16;
    return __builtin_bit_cast(float, v);
}
__device__ __forceinline__ u16 f2bf(float f) {   // round-to-nearest-even
    unsigned x = __builtin_bit_cast(unsigned, f);
    unsigned r = (x + 0x7fffu + ((x >> 16) & 1u)) >> 16;
    return (u16)r;
}
__device__ __forceinline__ void g2l16(const u16* g, u16* l) {
    // 16B per lane -> lds_base + lane*16 (wave-uniform LDS base)
    __builtin_amdgcn_global_load_lds((__attribute__((address_space(1))) void*)g,
                                     (__attribute__((address_space(3))) void*)l, 16, 0, 0);
}
__device__ __forceinline__ float gelu_tanh(float x) {
    // 0.5x(1+tanh(c)) == x * sigmoid(2c)
    float c = 1.5957691216057308f * (x + 0.044715f * x * x * x);
    return x * __frcp_rn(1.0f + __expf(-c));
}

// BK=64 LDS tiles: row = 128 B = 8 chunks of 16 B = exactly one 32-bank stripe.
// Swizzle phys_chunk = logical_chunk ^ (row & 7): conflict-free frag reads.
#define SW64(l)   (((((l) & 7) ^ (((l) >> 3) & 7))) * 8)
#define RS64(kk, quad, l15)  (((((kk) * 4 + (quad)) ^ ((l15) & 7))) * 8)

// ---------------- weight transposes + LN1 fused in ONE kernel ---------------
__global__ __launch_bounds__(256) void wtln(
        const float* __restrict__ Wq, const float* __restrict__ Wk,
        const float* __restrict__ Wv, const float* __restrict__ Wo,
        const float* __restrict__ W1, const float* __restrict__ W2,
        const float* __restrict__ W3,
        u16* __restrict__ WqkvT, u16* __restrict__ WoT,
        u16* __restrict__ W12T, u16* __restrict__ W3T,
        const float* __restrict__ x, const float* __restrict__ ln1_s,
        const float* __restrict__ ln1_b, u16* __restrict__ xn1) {
    __shared__ float tile[32][33];
    int blk = blockIdx.x;
    if (blk >= 16384) {
        int row = blk - 16384, t = threadIdx.x;
        float4 v = ((const float4*)(x + (size_t)row * 1024))[t];
        float sum = v.x + v.y + v.z + v.w;
        float sq  = v.x * v.x + v.y * v.y + v.z * v.z + v.w * v.w;
#pragma unroll
        for (int off = 1; off < 64; off <<= 1) {
            sum += __shfl_xor(sum, off);
            sq  += __shfl_xor(sq,  off);
        }
        float* s1 = &tile[0][0];
        float* s2 = &tile[0][8];
        int wave = t >> 6;
        if ((t & 63) == 0) { s1[wave] = sum; s2[wave] = sq; }
        __syncthreads();
        sum = s1[0] + s1[1] + s1[2] + s1[3];
        sq  = s2[0] + s2[1] + s2[2] + s2[3];
        float mean = sum * (1.0f / 1024.0f);
        float var  = sq  * (1.0f / 1024.0f) - mean * mean;
        float inv  = rsqrtf(var + 1e-6f);
        float4 sc = ((const float4*)ln1_s)[t], bb = ((const float4*)ln1_b)[t];
        u16x4 o;
        o[0] = f2bf((v.x - mean) * inv * sc.x + bb.x);
        o[1] = f2bf((v.y - mean) * inv * sc.y + bb.y);
        o[2] = f2bf((v.z - mean) * inv * sc.z + bb.z);
        o[3] = f2bf((v.w - mean) * inv * sc.w + bb.w);
        *(u16x4*)&xn1[(size_t)row * 1024 + t * 4] = o;
        return;
    }
    const float* W; u16* Wt; int R, C, local;
    if (blk < 3072) {
        int w = blk >> 10; local = blk & 1023;
        W = (w == 0) ? Wq : (w == 1) ? Wk : Wv;
        Wt = WqkvT + (size_t)w * 1024 * 1024; R = 1024; C = 1024;
    } else if (blk < 4096) { W = Wo; Wt = WoT; R = 1024; C = 1024; local = blk - 3072; }
    else if (blk < 8192)   { W = W1; Wt = W12T; R = 1024; C = 4096; local = blk - 4096; }
    else if (blk < 12288)  { W = W2; Wt = W12T + (size_t)4096 * 1024; R = 1024; C = 4096; local = blk - 8192; }
    else                   { W = W3; Wt = W3T; R = 4096; C = 1024; local = blk - 12288; }
    int tiles_x = C >> 5;
    int c0 = (local % tiles_x) * 32, r0 = (local / tiles_x) * 32;
    int tx = threadIdx.x & 31, ty = threadIdx.x >> 5;
#pragma unroll
    for (int i = 0; i < 32; i += 8)
        tile[ty + i][tx] = W[(size_t)(r0 + ty + i) * C + c0 + tx];
    __syncthreads();
#pragma unroll
    for (int i = 0; i < 32; i += 8)
        Wt[(size_t)(c0 + ty + i) * R + r0 + tx] = f2bf(tile[tx][ty + i]);
}

// ---- gemm64: 4-wave 128x128 block tile, 64x64 wave tile, BK=64 -------------
// EPI 0: bf16 partial store to o[kz] (split-K) | 4: QKV + per-head LN.
template <int EPI>
__global__ __launch_bounds__(256, 3) void gemm64(const u16* __restrict__ A,
                                                 const u16* __restrict__ Bt,
                                                 const float* __restrict__ bias,
                                                 const float* __restrict__ bias2,
                                                 const float* __restrict__ bias3,
                                                 const float* __restrict__ qn_s,
                                                 const float* __restrict__ qn_b,
                                                 const float* __restrict__ kn_s,
                                                 const float* __restrict__ kn_b,
                                                 u16* __restrict__ o0,
                                                 u16* __restrict__ o1,
                                                 u16* __restrict__ o2,
                                                 u16* __restrict__ o3,
                                                 int M, int N, int K, int Klen) {
    __shared__ u16 As[128 * 64];
    __shared__ u16 Bs[128 * 64];
    int tid = threadIdx.x, wave = tid >> 6, lane = tid & 63;
    int quad = lane >> 4, l15 = lane & 15;
    int row0 = blockIdx.y * 128, col0 = blockIdx.x * 128;
    int kz = blockIdx.z;
    int wr = (wave >> 1) * 64, wc = (wave & 1) * 64;
    int swz = SW64(lane);

    f32x4 acc[4][4] = {};

    const u16* gA = A  + (size_t)(row0 + wave * 32 + (lane >> 3)) * K + kz * Klen + swz;
    const u16* gB = Bt + (size_t)(col0 + wave * 32 + (lane >> 3)) * K + kz * Klen + swz;
    u16* lA = &As[wave * 32 * 64];
    u16* lB = &Bs[wave * 32 * 64];

    for (int k0 = 0; k0 < Klen; k0 += 64) {
        __syncthreads();
#pragma unroll
        for (int j = 0; j < 4; j++) {
            g2l16(gA + k0 + j * 8 * K, lA + j * 8 * 64);
            g2l16(gB + k0 + j * 8 * K, lB + j * 8 * 64);
        }
        __syncthreads();
#pragma unroll
        for (int kk = 0; kk < 2; kk++) {
            int rs = RS64(kk, quad, l15);
            bfrag af[4], bf[4];
#pragma unroll
            for (int mi = 0; mi < 4; mi++)
                af[mi] = *(const bfrag*)&As[(wr + mi * 16 + l15) * 64 + rs];
#pragma unroll
            for (int ni = 0; ni < 4; ni++)
                bf[ni] = *(const bfrag*)&Bs[(wc + ni * 16 + l15) * 64 + rs];
#pragma unroll
            for (int mi = 0; mi < 4; mi++)
#pragma unroll
                for (int ni = 0; ni < 4; ni++)
                    acc[mi][ni] = __builtin_amdgcn_mfma_f32_16x16x32_bf16(
                        af[mi], bf[ni], acc[mi][ni], 0, 0, 0);
        }
    }

    if (EPI == 0) {
        u16* P = (kz == 0) ? o0 : (kz == 1) ? o1 : (kz == 2) ? o2 : o3;
#pragma unroll
        for (int mi = 0; mi < 4; mi++) {
            int rbase = row0 + wr + mi * 16 + quad * 4;
#pragma unroll
            for (int r = 0; r < 4; r++)
#pragma unroll
                for (int ni = 0; ni < 4; ni++)
                    P[(size_t)(rbase + r) * N + col0 + wc + ni * 16 + l15] =
                        f2bf(acc[mi][ni][r]);
        }
    } else {
        int cbase = col0 + wc;
        int z = cbase >> 10;              // 0=q, 1=k, 2=v
        int hd = (cbase >> 6) & 15;
        const float* bp = (z == 0) ? bias : (z == 1) ? bias2 : bias3;
        float post = (z == 0) ? 0.125f : 1.0f;
        float bv[4], sn[4], bn[4];
#pragma unroll
        for (int ni = 0; ni < 4; ni++)
            bv[ni] = bp[(cbase & 1023) + ni * 16 + l15];
        if (z < 2) {
            const float* ns = (z == 0) ? qn_s : kn_s;
            const float* nb = (z == 0) ? qn_b : kn_b;
#pragma unroll
            for (int ni = 0; ni < 4; ni++) {
                sn[ni] = ns[hd * 64 + ni * 16 + l15];
                bn[ni] = nb[hd * 64 + ni * 16 + l15];
            }
        }
#pragma unroll
        for (int mi = 0; mi < 4; mi++) {
            int rbase = row0 + wr + mi * 16 + quad * 4;
#pragma unroll
            for (int r = 0; r < 4; r++) {
                float v0 = acc[mi][0][r] + bv[0];
                float v1 = acc[mi][1][r] + bv[1];
                float v2 = acc[mi][2][r] + bv[2];
                float v3 = acc[mi][3][r] + bv[3];
                size_t rb = (size_t)(rbase + r) * N + cbase;
                if (z == 2) {
                    o0[rb + 0 * 16 + l15] = f2bf(v0);
                    o0[rb + 1 * 16 + l15] = f2bf(v1);
                    o0[rb + 2 * 16 + l15] = f2bf(v2);
                    o0[rb + 3 * 16 + l15] = f2bf(v3);
                } else {
                    float s  = v0 + v1 + v2 + v3;
                    float sq = v0 * v0 + v1 * v1 + v2 * v2 + v3 * v3;
#pragma unroll
                    for (int m = 1; m < 16; m <<= 1) {
                        s  += __shfl_xor(s,  m);
                        sq += __shfl_xor(sq, m);
                    }
                    float mean = s * (1.0f / 64.0f);
                    float var  = sq * (1.0f / 64.0f) - mean * mean;
                    float inv  = rsqrtf(var + 1e-6f);
                    o0[rb + 0 * 16 + l15] = f2bf(((v0 - mean) * inv * sn[0] + bn[0]) * post);
                    o0[rb + 1 * 16 + l15] = f2bf(((v1 - mean) * inv * sn[1] + bn[1]) * post);
                    o0[rb + 2 * 16 + l15] = f2bf(((v2 - mean) * inv * sn[2] + bn[2]) * post);
                    o0[rb + 3 * 16 + l15] = f2bf(((v3 - mean) * inv * sn[3] + bn[3]) * post);
                }
            }
        }
    }
}

// ---------------- fused GeGLU FFN GEMM: dbuf, ONE barrier per K-step --------
// 512 threads = 8 waves (4M x 2N), block tile 256M x 128N, wave 64x64 (x1+x2),
// BK=64. LDS = 2 x (A 32K + B1 16K + B2 16K) = 128 KiB -> 1 block/CU, but the
// single-barrier structure lets the 8 waves' ds_reads/MFMAs interleave freely
// within a K-step; staging for step t+1 is issued at the TOP of step t, so the
// compiler's vmcnt(0) drain at the closing __syncthreads waits on ~2400-cyc-old
// loads (HBM latency fully covered). Per-CU step: MFMA 2484 cyc > LDS 2048 cyc
// -> MFMA-bound. Epilogue needs no exchange: each thread owns matching
// x1/x2 accumulators. Swizzle (SW64/RS64) identical to the proven R0 kernel.
__global__ __launch_bounds__(512, 2) void gemm_w12(const u16* __restrict__ A,
                                                   const u16* __restrict__ W12T,
                                                   const float* __restrict__ b1,
                                                   const float* __restrict__ b2,
                                                   u16* __restrict__ H) {
    extern __shared__ __align__(16) u16 sm[];   // 2 x 32768 u16
    int tid = threadIdx.x, w = tid >> 6, lane = tid & 63;
    int quad = lane >> 4, l15 = lane & 15;
    int row0 = blockIdx.y * 256, col0 = blockIdx.x * 128;
    int wr = (w >> 1) * 64, wc = (w & 1) * 64;
    int swz8 = SW64(lane);

    f32x4 acc1[4][4] = {}, acc2[4][4] = {};

    // staging bases: wave w stages rows {j*64 + w*8 + (lane>>3)}
    const u16* gA  = A    + (size_t)(row0 + w * 8 + (lane >> 3)) * 1024 + swz8;
    const u16* gB1 = W12T + (size_t)(col0 + w * 8 + (lane >> 3)) * 1024 + swz8;
    const u16* gB2 = gB1  + (size_t)4096 * 1024;

    auto stage = [&](int bufi, int t) {
        u16* base = sm + bufi * 32768;
        const u16* ga  = gA  + t * 64;
        const u16* gb1 = gB1 + t * 64;
        const u16* gb2 = gB2 + t * 64;
#pragma unroll
        for (int j = 0; j < 4; j++)               // A: 256 rows
            g2l16(ga + (size_t)j * 64 * 1024, base + (j * 64 + w * 8) * 64);
#pragma unroll
        for (int j = 0; j < 2; j++) {             // B1/B2: 128 rows each
            g2l16(gb1 + (size_t)j * 64 * 1024, base + 16384 + (j * 64 + w * 8) * 64);
            g2l16(gb2 + (size_t)j * 64 * 1024, base + 24576 + (j * 64 + w * 8) * 64);
        }
    };

    stage(0, 0);
    __syncthreads();                              // drains vmcnt(0): buf0 ready

    for (int t = 0; t < 16; ++t) {
        if (t < 15) stage((t + 1) & 1, t + 1);    // issue next-step loads FIRST
        const u16* lA  = sm + (t & 1) * 32768;
        const u16* lB1 = lA + 16384;
        const u16* lB2 = lA + 24576;
#pragma unroll
        for (int kk = 0; kk < 2; kk++) {
            int rs = RS64(kk, quad, l15);
            bfrag af[4], b1f[4], b2f[4];
#pragma unroll
            for (int mi = 0; mi < 4; mi++)
                af[mi] = *(const bfrag*)&lA[(wr + mi * 16 + l15) * 64 + rs];
#pragma unroll
            for (int ni = 0; ni < 4; ni++) {
                b1f[ni] = *(const bfrag*)&lB1[(wc + ni * 16 + l15) * 64 + rs];
                b2f[ni] = *(const bfrag*)&lB2[(wc + ni * 16 + l15) * 64 + rs];
            }
#pragma unroll
            for (int mi = 0; mi < 4; mi++)
#pragma unroll
                for (int ni = 0; ni < 4; ni++) {
                    acc1[mi][ni] = __builtin_amdgcn_mfma_f32_16x16x32_bf16(
                        af[mi], b1f[ni], acc1[mi][ni], 0, 0, 0);
                    acc2[mi][ni] = __builtin_amdgcn_mfma_f32_16x16x32_bf16(
                        af[mi], b2f[ni], acc2[mi][ni], 0, 0, 0);
                }
        }
        __syncthreads();   // ONE barrier/step: drains stage loads + frag reads
    }

    float bv1[4], bv2[4];
    int cols[4];
#pragma unroll
    for (int ni = 0; ni < 4; ni++) {
        cols[ni] = col0 + wc + ni * 16 + l15;
        bv1[ni] = b1[cols[ni]];
        bv2[ni] = b2[cols[ni]];
    }
#pragma unroll
    for (int mi = 0; mi < 4; mi++) {
        int rbase = row0 + wr + mi * 16 + quad * 4;
#pragma unroll
        for (int r = 0; r < 4; r++) {
#pragma unroll
            for (int ni = 0; ni < 4; ni++) {
                float x1 = acc1[mi][ni][r] + bv1[ni];
                float x2 = acc2[mi][ni][r] + bv2[ni];
                H[(size_t)(rbase + r) * 4096 + cols[ni]] = f2bf(x1 * gelu_tanh(x2));
            }
        }
    }
}

// ---- fused Wo-reduce + residual + LN2 --------------------------------------
__global__ __launch_bounds__(256) void reduce_ln(const u16* __restrict__ p0,
                                                 const u16* __restrict__ p1,
                                                 const float* __restrict__ x,
                                                 const float* __restrict__ bo,
                                                 const float* __restrict__ s,
                                                 const float* __restrict__ b,
                                                 float* __restrict__ xmid,
                                                 u16* __restrict__ xn2) {
    int row = blockIdx.x, t = threadIdx.x;
    size_t i = (size_t)row * 1024 + t * 4;
    float4 xv = *(const float4*)&x[i];
    float4 bb = *(const float4*)&bo[t * 4];
    u16x4 a0 = *(const u16x4*)&p0[i];
    u16x4 a1 = *(const u16x4*)&p1[i];
    float4 v;
    v.x = xv.x + bb.x + bf2f(a0[0]) + bf2f(a1[0]);
    v.y = xv.y + bb.y + bf2f(a0[1]) + bf2f(a1[1]);
    v.z = xv.z + bb.z + bf2f(a0[2]) + bf2f(a1[2]);
    v.w = xv.w + bb.w + bf2f(a0[3]) + bf2f(a1[3]);
    *(float4*)&xmid[i] = v;
    float sum = v.x + v.y + v.z + v.w;
    float sq  = v.x * v.x + v.y * v.y + v.z * v.z + v.w * v.w;
#pragma unroll
    for (int off = 1; off < 64; off <<= 1) {
        sum += __shfl_xor(sum, off);
        sq  += __shfl_xor(sq,  off);
    }
    __shared__ float s1[4], s2[4];
    int wave = t >> 6;
    if ((t & 63) == 0) { s1[wave] = sum; s2[wave] = sq; }
    __syncthreads();
    sum = s1[0] + s1[1] + s1[2] + s1[3];
    sq  = s2[0] + s2[1] + s2[2] + s2[3];
    float mean = sum * (1.0f / 1024.0f);
    float var  = sq  * (1.0f / 1024.0f) - mean * mean;
    float inv  = rsqrtf(var + 1e-6f);
    float4 sc = ((const float4*)s)[t], lb = ((const float4*)b)[t];
    u16x4 o;
    o[0] = f2bf((v.x - mean) * inv * sc.x + lb.x);
    o[1] = f2bf((v.y - mean) * inv * sc.y + lb.y);
    o[2] = f2bf((v.z - mean) * inv * sc.z + lb.z);
    o[3] = f2bf((v.w - mean) * inv * sc.w + lb.w);
    *(u16x4*)&xn2[i] = o;
}

// ---------------- reduce: out = xmid + b3 + sum of 4 bf16 partials ----------
__global__ __launch_bounds__(256) void reduce4(const u16* __restrict__ p0,
                                               const u16* __restrict__ p1,
                                               const u16* __restrict__ p2,
                                               const u16* __restrict__ p3,
                                               const float* __restrict__ xmid,
                                               const float* __restrict__ b3,
                                               float* __restrict__ out) {
    size_t i = ((size_t)blockIdx.x * 256 + threadIdx.x) * 4;
    float4 xm = *(const float4*)&xmid[i];
    float4 bb = *(const float4*)&b3[i & 1023];
    u16x4 a0 = *(const u16x4*)&p0[i];
    u16x4 a1 = *(const u16x4*)&p1[i];
    u16x4 a2 = *(const u16x4*)&p2[i];
    u16x4 a3 = *(const u16x4*)&p3[i];
    float4 o;
    o.x = xm.x + bb.x + bf2f(a0[0]) + bf2f(a1[0]) + bf2f(a2[0]) + bf2f(a3[0]);
    o.y = xm.y + bb.y + bf2f(a0[1]) + bf2f(a1[1]) + bf2f(a2[1]) + bf2f(a3[1]);
    o.z = xm.z + bb.z + bf2f(a0[2]) + bf2f(a1[2]) + bf2f(a2[2]) + bf2f(a3[2]);
    o.w = xm.w + bb.w + bf2f(a0[3]) + bf2f(a1[3]) + bf2f(a2[3]) + bf2f(a3[3]);
    *(float4*)&out[i] = o;
}

// ---------------- Flash attention v2 ----------------------------------------
// grid (16 qt, 16 h, 4 b); 256 threads; 64-row Q tiles (16 rows/wave).
// Q frags direct from global; no-max softmax (|s|<=8 guaranteed by QK-norm:
// ||q*0.125||=1, ||k||=8 -> exp(s) <= e^8, fp32-safe); lane-local l partials
// reduced once in the epilogue. Vt staged seg=wave/key=lane (conflict-free
// ds_write_b16); Ps stride 68 u16 (quad bank-groups disjoint; b64-aligned).
#define LPK 72
#define LPV 72
#define LPP 68
__global__ __launch_bounds__(256, 4) void flash(const u16* __restrict__ qkv,
                                                u16* __restrict__ o) {
    int qt = blockIdx.x, h = blockIdx.y, b = blockIdx.z;
    int tid = threadIdx.x, wave = tid >> 6, lane = tid & 63;
    int quad = lane >> 4, l15 = lane & 15;

    __shared__ u16 Ks[64 * LPK];
    __shared__ u16 Vt[64 * LPV];   // [d][key]
    __shared__ u16 Ps[64 * LPP];

    // Q A-fragments straight from global (rows wave*16+l15, 16B contiguous)
    const u16* qrow = qkv + (size_t)(b * 1024 + qt * 64 + wave * 16 + l15) * 3072
                      + h * 64 + quad * 8;
    bfrag aq0 = *(const bfrag*)qrow;
    bfrag aq1 = *(const bfrag*)(qrow + 32);

    f32x4 accO[4] = {};
    float l_run[4] = {0.f, 0.f, 0.f, 0.f};

    for (int kt = 0; kt < 16; kt++) {
        __syncthreads();
        {   // K rows: row = tid>>2, seg = tid&3 (vector writes)
            int row = tid >> 2, seg = tid & 3;
            const u16* ksrc = qkv + (size_t)(b * 1024 + kt * 64 + row) * 3072
                              + 1024 + h * 64 + seg * 16;
            *(u16x8*)&Ks[row * LPK + seg * 16]     = *(const u16x8*)ksrc;
            *(u16x8*)&Ks[row * LPK + seg * 16 + 8] = *(const u16x8*)(ksrc + 8);
        }
        {   // V transposed: seg = wave, key = lane -> 64 consecutive u16/write
            const u16* vsrc = qkv + (size_t)(b * 1024 + kt * 64 + lane) * 3072
                              + 2048 + h * 64 + wave * 16;
            u16x8 v0 = *(const u16x8*)vsrc, v1 = *(const u16x8*)(vsrc + 8);
#pragma unroll
            for (int j = 0; j < 8; j++) Vt[(wave * 16 + j) * LPV + lane]     = v0[j];
#pragma unroll
            for (int j = 0; j < 8; j++) Vt[(wave * 16 + 8 + j) * LPV + lane] = v1[j];
        }
        __syncthreads();

        // S = Q x K^T over 64 keys
        f32x4 accS[4] = {};
#pragma unroll
        for (int ct = 0; ct < 4; ct++) {
            bfrag bk0 = *(const bfrag*)&Ks[(ct * 16 + l15) * LPK + quad * 8];
            bfrag bk1 = *(const bfrag*)&Ks[(ct * 16 + l15) * LPK + 32 + quad * 8];
            accS[ct] = __builtin_amdgcn_mfma_f32_16x16x32_bf16(aq0, bk0, accS[ct], 0, 0, 0);
            accS[ct] = __builtin_amdgcn_mfma_f32_16x16x32_bf16(aq1, bk1, accS[ct], 0, 0, 0);
        }

        // p = exp(s) (no max needed), lane-local l partial, write P
#pragma unroll
        for (int r = 0; r < 4; r++) {
            float p0 = __expf(accS[0][r]);
            float p1 = __expf(accS[1][r]);
            float p2 = __expf(accS[2][r]);
            float p3 = __expf(accS[3][r]);
            l_run[r] += (p0 + p1) + (p2 + p3);
            int pbase = (wave * 16 + quad * 4 + r) * LPP + l15;
            Ps[pbase + 0]  = f2bf(p0);
            Ps[pbase + 16] = f2bf(p1);
            Ps[pbase + 32] = f2bf(p2);
            Ps[pbase + 48] = f2bf(p3);
        }

        // O += P x V  (ap via two b64 reads; Vt rows give b128 B-frags)
#pragma unroll
        for (int kk = 0; kk < 2; kk++) {
            const u16* pp = &Ps[(wave * 16 + l15) * LPP + kk * 32 + quad * 8];
            u16x4 lo = *(const u16x4*)pp;
            u16x4 hi = *(const u16x4*)(pp + 4);
            u16x8 apu;
            apu[0] = lo[0]; apu[1] = lo[1]; apu[2] = lo[2]; apu[3] = lo[3];
            apu[4] = hi[0]; apu[5] = hi[1]; apu[6] = hi[2]; apu[7] = hi[3];
            bfrag ap = __builtin_bit_cast(bfrag, apu);
#pragma unroll
            for (int oc = 0; oc < 4; oc++) {
                bfrag bv = *(const bfrag*)&Vt[(oc * 16 + l15) * LPV + kk * 32 + quad * 8];
                accO[oc] = __builtin_amdgcn_mfma_f32_16x16x32_bf16(ap, bv, accO[oc], 0, 0, 0);
            }
        }
    }

    // epilogue: reduce l over the 16 row-lanes, normalize, store
#pragma unroll
    for (int r = 0; r < 4; r++) {
        float l = l_run[r];
#pragma unroll
        for (int m = 1; m < 16; m <<= 1) l += __shfl_xor(l, m);
        float linv = 1.0f / l;
        int srow = qt * 64 + wave * 16 + quad * 4 + r;
#pragma unroll
        for (int oc = 0; oc < 4; oc++)
            o[(size_t)(b * 1024 + srow) * 1024 + h * 64 + oc * 16 + l15] =
                f2bf(accO[oc][r] * linv);
    }
}

// ---------------------------------------------------------------------------
extern "C" void kernel_launch(void* const* d_in, const int* in_sizes, int n_in,
                              void* d_out, int out_size, void* d_ws, size_t ws_size,
                              hipStream_t stream) {
    const float* x     = (const float*)d_in[0];
    const float* ln1_s = (const float*)d_in[2];
    const float* ln1_b = (const float*)d_in[3];
    const float* Wq = (const float*)d_in[4];  const float* bq = (const float*)d_in[5];
    const float* Wk = (const float*)d_in[6];  const float* bk = (const float*)d_in[7];
    const float* Wv = (const float*)d_in[8];  const float* bv = (const float*)d_in[9];
    const float* qn_s = (const float*)d_in[10]; const float* qn_b = (const float*)d_in[11];
    const float* kn_s = (const float*)d_in[12]; const float* kn_b = (const float*)d_in[13];
    const float* Wo = (const float*)d_in[14]; const float* bo = (const float*)d_in[15];
    const float* ln2_s = (const float*)d_in[16]; const float* ln2_b = (const float*)d_in[17];
    const float* W1 = (const float*)d_in[18]; const float* b1 = (const float*)d_in[19];
    const float* W2 = (const float*)d_in[20]; const float* b2 = (const float*)d_in[21];
    const float* W3 = (const float*)d_in[22]; const float* b3 = (const float*)d_in[23];
    float* out = (float*)d_out;

    char* ws = (char*)d_ws;
    const size_t MB = (size_t)1 << 20;
    u16* WqkvT = (u16*)(ws + 0);         // 0..6    dead after QKV; then p0 @0
    u16* WoT   = (u16*)(ws + 6 * MB);    // 6..8    dead after Wo
    u16* W12T  = (u16*)(ws + 8 * MB);    // 8..24   dead after W12; then p1/p2
    u16* W3T   = (u16*)(ws + 24 * MB);   // 24..32  dead after splitk
    u16* xn1   = (u16*)(ws + 32 * MB);   // 32..40  dead after QKV
    u16* attn  = (u16*)(ws + 32 * MB);   //   reuse: dead after Wo-gemm
    u16* xn2   = (u16*)(ws + 32 * MB);   //   reuse: dead after W12
    u16* qkv   = (u16*)(ws + 40 * MB);   // 40..64  dead after flash
    float* xmid = (float*)(ws + 40 * MB);//   reuse: 40..56, alive until reduce4
    u16* p3    = (u16*)(ws + 56 * MB);   // 56..64
    u16* h     = (u16*)(ws + 64 * MB);   // 64..96  dead after splitk
    u16* wp0   = (u16*)(ws + 64 * MB);   // Wo partials: 64..72, 72..80
    u16* wp1   = (u16*)(ws + 72 * MB);   //   dead after reduce_ln (before h)
    u16* p0    = (u16*)(ws + 0);
    u16* p1    = (u16*)(ws + 8 * MB);
    u16* p2    = (u16*)(ws + 16 * MB);
    // peak = 96 MB

    wtln<<<20480, 256, 0, stream>>>(Wq, Wk, Wv, Wo, W1, W2, W3,
                                    WqkvT, WoT, W12T, W3T,
                                    x, ln1_s, ln1_b, xn1);

    // fused QKV + per-head QK-norm (BK=64)
    gemm64<4><<<dim3(24, 32, 1), 256, 0, stream>>>(
        xn1, WqkvT, bq, bk, bv, qn_s, qn_b, kn_s, kn_b,
        qkv, nullptr, nullptr, nullptr, 4096, 3072, 1024, 1024);

    flash<<<dim3(16, 16, 4), 256, 0, stream>>>(qkv, attn);

    // Wo split-K=2 partials (BK=64)
    gemm64<0><<<dim3(8, 32, 2), 256, 0, stream>>>(
        attn, WoT, nullptr, nullptr, nullptr, nullptr, nullptr, nullptr, nullptr,
        wp0, wp1, nullptr, nullptr, 4096, 1024, 1024, 512);

    // xmid = x + bo + wp0 + wp1; xn2 = LN2(xmid)
    reduce_ln<<<4096, 256, 0, stream>>>(wp0, wp1, x, bo, ln2_s, ln2_b, xmid, xn2);

    // fused GeGLU FFN: 256x128 tile, dbuf, one barrier/K-step, 128 KiB LDS
    gemm_w12<<<dim3(32, 16), 512, 131072, stream>>>(xn2, W12T, b1, b2, h);

    // W3 split-K=4 partials (BK=64)
    gemm64<0><<<dim3(8, 32, 4), 256, 0, stream>>>(
        h, W3T, nullptr, nullptr, nullptr, nullptr, nullptr, nullptr, nullptr,
        p0, p1, p2, p3, 4096, 1024, 4096, 1024);

    // out = xmid + b3 + sum(partials)
    reduce4<<<4096, 256, 0, stream>>>(p0, p1, p2, p3, xmid, b3, out);
}